// Round 2
// baseline (1070.890 us; speedup 1.0000x reference)
//
#include <hip/hip_runtime.h>
#include <math.h>

// ---------------- constants ----------------
#define NN 50000
#define EE 800000
#define ETOT (EE + NN)
#define BB 128
#define DIM 128
#define GHID 32
#define CHUNK 64
#define NCHUNK ((ETOT + CHUNK - 1) / CHUNK)
#define SCB 196  // scan blocks: 196*256 >= 50000

typedef _Float16 f16;
typedef _Float16 f16x2 __attribute__((ext_vector_type(2)));
typedef _Float16 f16x8 __attribute__((ext_vector_type(8)));
typedef float f32x4 __attribute__((ext_vector_type(4)));

struct CurvPack {
  float k[4], sk[4], mx[4], thr2[4];
};

// ---------------- device math helpers ----------------
__device__ __forceinline__ float wsum64(float v) {
#pragma unroll
  for (int m = 32; m; m >>= 1) v += __shfl_xor(v, m, 64);
  return v;
}

__device__ __forceinline__ float tan_k_d(float x, float kv, float sk) {
  if (kv > 0.f) return tanf(x * sk) / sk;
  if (kv < 0.f) return tanhf(x * sk) / sk;
  return x;
}

__device__ __forceinline__ float artan_k_d(float x, float kv, float sk) {
  if (kv > 0.f) return atanf(x * sk) / sk;
  if (kv < 0.f) {
    float t = x * sk;
    t = fminf(fmaxf(t, -1.f + 1e-7f), 1.f - 1e-7f);
    return atanhf(t) / sk;
  }
  return x;
}

__device__ __forceinline__ float proj_scale_d(float n, float kv, float maxn) {
  if (kv < 0.f && n > maxn) return maxn / n;
  return 1.f;
}

// ---------------- graph preprocessing ----------------
__global__ void k_init(float* __restrict__ deg, int n) {
  int i = blockIdx.x * 256 + threadIdx.x;
  if (i < n) deg[i] = 1.0f;  // self loop
}

__global__ void k_counts(const int* __restrict__ batch, int* __restrict__ boff,
                         float* __restrict__ counts, int n) {
  int b = threadIdx.x;
  if (b <= 128) {
    int lo = 0, hi = n;
    while (lo < hi) {
      int mid = (lo + hi) >> 1;
      if (batch[mid] < b) lo = mid + 1; else hi = mid;
    }
    boff[b] = lo;
  }
  __syncthreads();
  if (b < 128) counts[b] = (float)(boff[b + 1] - boff[b]);
}

__global__ void k_deg(const int* __restrict__ ei, float* __restrict__ deg, int e) {
  int i = blockIdx.x * 256 + threadIdx.x;
  if (i < e) atomicAdd(&deg[ei[e + i]], 1.0f);
}

__global__ void k_dinv(float* __restrict__ deg, int* __restrict__ ideg, int n) {
  int i = blockIdx.x * 256 + threadIdx.x;
  if (i < n) {
    float d = deg[i];
    ideg[i] = (int)(d + 0.5f);
    deg[i] = 1.0f / sqrtf(d);
  }
}

// ---------------- parallel scan ----------------
__global__ void k_scanA(const int* __restrict__ ideg, int* __restrict__ bsum, int n) {
  __shared__ int ls[4];
  int i = blockIdx.x * 256 + threadIdx.x;
  int v = (i < n) ? ideg[i] : 0;
#pragma unroll
  for (int m = 1; m < 64; m <<= 1) v += __shfl_xor(v, m, 64);
  if ((threadIdx.x & 63) == 0) ls[threadIdx.x >> 6] = v;
  __syncthreads();
  if (threadIdx.x == 0) bsum[blockIdx.x] = ls[0] + ls[1] + ls[2] + ls[3];
}

__global__ void k_scanB(int* __restrict__ bsum, int nb) {
  __shared__ int wsh[4];
  int tid = threadIdx.x;
  int lane = tid & 63, w = tid >> 6;
  int v = (tid < nb) ? bsum[tid] : 0;
  int x = v;
#pragma unroll
  for (int o = 1; o < 64; o <<= 1) {
    int t = __shfl_up(x, o, 64);
    if (lane >= o) x += t;
  }
  if (lane == 63) wsh[w] = x;
  __syncthreads();
  int add = 0;
  for (int k2 = 0; k2 < w; k2++) add += wsh[k2];
  if (tid < nb) bsum[tid] = add + x - v;
}

__global__ void k_scanC(const int* __restrict__ ideg, const int* __restrict__ bsum,
                        int* __restrict__ off, int* __restrict__ cursor, int n) {
  __shared__ int wsh[4];
  int i = blockIdx.x * 256 + threadIdx.x;
  int lane = threadIdx.x & 63, w = threadIdx.x >> 6;
  int v = (i < n) ? ideg[i] : 0;
  int x = v;
#pragma unroll
  for (int o = 1; o < 64; o <<= 1) {
    int t = __shfl_up(x, o, 64);
    if (lane >= o) x += t;
  }
  if (lane == 63) wsh[w] = x;
  __syncthreads();
  int add = bsum[blockIdx.x];
  for (int k2 = 0; k2 < w; k2++) add += wsh[k2];
  int excl = add + x - v;
  if (i < n) {
    off[i] = excl;
    cursor[i] = excl;
  }
  if (i == n - 1) off[n] = excl + v;
}

// ---------------- chunk head nodes + first-occurrence slots ----------------
__global__ void k_bnodes(const int* __restrict__ off, int* __restrict__ bnode, int nchunk,
                         int n) {
  int g = blockIdx.x * 256 + threadIdx.x;
  if (g >= nchunk) return;
  int e0 = g * CHUNK;
  int lo = 0, hi = n;
  while (hi - lo > 1) {
    int mid = (lo + hi) >> 1;
    if (off[mid] <= e0) lo = mid; else hi = mid;
  }
  bnode[g] = lo;
}

__global__ void k_bslot(const int* __restrict__ bnode, int* __restrict__ bslot, int nchunk) {
  int g = blockIdx.x * 256 + threadIdx.x;
  if (g >= nchunk) return;
  int v = bnode[g];
  int lo = 0, hi = g;
  while (lo < hi) {
    int mid = (lo + hi) >> 1;
    if (bnode[mid] < v) lo = mid + 1; else hi = mid;
  }
  bslot[g] = lo;
}

__device__ __forceinline__ bool span_head(const int* bnode, const int* bslot, const int* off,
                                          int g, int& nd) {
  if (bslot[g] != g) return false;
  nd = bnode[g];
  int s = off[nd], e = off[nd + 1];
  return (s / CHUNK) != ((e - 1) / CHUNK);
}

// zero spanning boundary slots of aggc (640 floats per slot)
__global__ void k_zeroc(const int* __restrict__ bnode, const int* __restrict__ bslot,
                        const int* __restrict__ off, float* __restrict__ aggc, int nchunk) {
  int g = blockIdx.x * 4 + (threadIdx.x >> 6);
  int lane = threadIdx.x & 63;
  if (g >= nchunk) return;
  int nd;
  if (!span_head(bnode, bslot, off, g, nd)) return;
  float2 z = make_float2(0.f, 0.f);
#pragma unroll
  for (int i = 0; i < 5; i++) ((float2*)aggc)[(size_t)g * 320 + i * 64 + lane] = z;
}

// ---------------- edge placement ----------------
__global__ void k_place(const int* __restrict__ ei, const float* __restrict__ dinv,
                        int* __restrict__ cursor, int2* __restrict__ esw, int e, int n) {
  int i = blockIdx.x * 256 + threadIdx.x;
  int et = e + n;
  if (i >= et) return;
  int r_, c_;
  if (i < e) {
    r_ = ei[i];
    c_ = ei[e + i];
  } else {
    r_ = i - e;
    c_ = i - e;
  }
  int p = atomicAdd(&cursor[c_], 1);
  esw[p] = make_int2(r_, __float_as_int(dinv[r_] * dinv[c_]));
}

// ---------------- bias points ----------------
__global__ void k_biaspt_all(const float* __restrict__ eb1, const float* __restrict__ eb2,
                             float* __restrict__ biasb, CurvPack cp) {
  __shared__ float l2[2];
  int blk = blockIdx.x;  // ex*2 + layer
  int ex = blk >> 1, layer = blk & 1;
  float kv = cp.k[ex], sk = cp.sk[ex], maxn = cp.mx[ex];
  const float* b = (layer ? eb2 : eb1) + ex * 128;
  float* outb = biasb + blk * 132;
  int j = threadIdx.x;
  float v = b[j];
  float n2 = wsum64(v * v);
  if ((j & 63) == 0) l2[j >> 6] = n2;
  __syncthreads();
  n2 = l2[0] + l2[1];
  float nraw = sqrtf(n2);
  float nnv = fmaxf(nraw, 1e-15f);
  float tk = tan_k_d(nnv, kv, sk);
  float s = tk / nnv;
  float pn = fmaxf(fabsf(tk) * (nraw / nnv), 1e-15f);
  float ps = proj_scale_d(pn, kv, maxn);
  float bp = ps * s * v;
  outb[j] = bp;
  float y2v = wsum64(bp * bp);
  __syncthreads();
  if ((j & 63) == 0) l2[j >> 6] = y2v;
  __syncthreads();
  if (j == 0) outb[128] = l2[0] + l2[1];
}

// ---------------- W -> fp16 hi/lo split ----------------
__global__ void k_w2h(const float* __restrict__ ew1, const float* __restrict__ ew2,
                      f16* __restrict__ whi, f16* __restrict__ wlo) {
  int i = blockIdx.x * 256 + threadIdx.x;
  if (i >= 8 * 16384) return;
  int slot = i >> 14;
  int r = i & 16383;
  int ex = slot >> 1, layer = slot & 1;
  float w = (layer ? ew2 : ew1)[ex * 16384 + r];
  f16 h = (f16)w;
  whi[i] = h;
  wlo[i] = (f16)(w - (float)h);
}

// ---------------- MFMA expert GEMM (fp32 A split in-kernel; A-row norm fused) -------
// grid.y = expert. Output t interleaved: half offset (d>>1)*8 + ex*2 + (d&1).
__global__ __launch_bounds__(256) void k_matmfma(
    const float* __restrict__ A, int astr, int aoffPerEx,
    const f16* __restrict__ whiB, const f16* __restrict__ wloB,
    const float* __restrict__ biasB, int layer, f16* __restrict__ tout, int n,
    CurvPack cp) {
  __shared__ float red[3][16][4];
  __shared__ float redT[16][4];
  __shared__ float nAs[16], nCs[16], nL[16];
  int ex = blockIdx.y;
  float kv = cp.k[ex], sk = cp.sk[ex], maxn = cp.mx[ex];
  const f16* whi = whiB + (size_t)(ex * 2 + layer) * 16384;
  const f16* wlo = wloB + (size_t)(ex * 2 + layer) * 16384;
  const float* biasb = biasB + (ex * 2 + layer) * 132;

  int tid = threadIdx.x;
  int w = tid >> 6;
  int lane = tid & 63;
  int col = lane & 15;
  int quad = lane >> 4;
  int n0w = blockIdx.x * 16;
  if (n0w >= n) return;

  int anodec = min(n0w + col, n - 1);
  const float* arow = A + (size_t)anodec * astr + ex * aoffPerEx;
  int jt0 = w * 2;

  f32x4 acc[2];
  acc[0] = (f32x4){0.f, 0.f, 0.f, 0.f};
  acc[1] = (f32x4){0.f, 0.f, 0.f, 0.f};
  float a_n2 = 0.f;

#pragma unroll
  for (int kc = 0; kc < 4; kc++) {
    int kb = kc * 32 + quad * 8;
    float4 a0 = *(const float4*)(arow + kb);
    float4 a1 = *(const float4*)(arow + kb + 4);
    float av[8] = {a0.x, a0.y, a0.z, a0.w, a1.x, a1.y, a1.z, a1.w};
    f16x8 Ah, Al;
#pragma unroll
    for (int i = 0; i < 8; i++) {
      a_n2 = fmaf(av[i], av[i], a_n2);
      f16 h = (f16)av[i];
      Ah[i] = h;
      Al[i] = (f16)(av[i] - (float)h);
    }
#pragma unroll
    for (int j2 = 0; j2 < 2; j2++) {
      const f16* bh = whi + (size_t)((jt0 + j2) * 16 + col) * 128 + kb;
      const f16* bl = wlo + (size_t)((jt0 + j2) * 16 + col) * 128 + kb;
      f16x8 Bh = *(const f16x8*)bh;
      f16x8 Bl = *(const f16x8*)bl;
      acc[j2] = __builtin_amdgcn_mfma_f32_16x16x32_f16(Ah, Bh, acc[j2], 0, 0, 0);
      acc[j2] = __builtin_amdgcn_mfma_f32_16x16x32_f16(Ah, Bl, acc[j2], 0, 0, 0);
      acc[j2] = __builtin_amdgcn_mfma_f32_16x16x32_f16(Al, Bh, acc[j2], 0, 0, 0);
    }
  }
  // reduce per-quad partial norms across quads (per col)
  a_n2 += __shfl_xor(a_n2, 16, 64);
  a_n2 += __shfl_xor(a_n2, 32, 64);

  float bpj[2];
  bpj[0] = biasb[jt0 * 16 + col];
  bpj[1] = biasb[(jt0 + 1) * 16 + col];
  float y2 = biasb[128];

#pragma unroll
  for (int r = 0; r < 4; r++) {
    float s0 = 0.f, s1 = 0.f, s2 = 0.f;
#pragma unroll
    for (int j2 = 0; j2 < 2; j2++) {
      float v = acc[j2][r];
      s0 = fmaf(v, v, s0);
      s1 += fabsf(v);
      s2 = fmaf(v, bpj[j2], s2);
    }
#pragma unroll
    for (int m = 1; m < 16; m <<= 1) {
      s0 += __shfl_xor(s0, m, 64);
      s1 += __shfl_xor(s1, m, 64);
      s2 += __shfl_xor(s2, m, 64);
    }
    if (col == 0) {
      red[0][quad * 4 + r][w] = s0;
      red[1][quad * 4 + r][w] = s1;
      red[2][quad * 4 + r][w] = s2;
    }
  }
  __syncthreads();

  if (tid < 16) {
    // expmap0 scale from the A-row norm (was k_nodeprep / MODE0-flush)
    float nraw0 = sqrtf(a_n2);
    float nnv0 = fmaxf(nraw0, 1e-15f);
    float tk0 = tan_k_d(nnv0, kv, sk);
    float pn0 = fmaxf(fabsf(tk0) * (nraw0 / nnv0), 1e-15f);
    float ps0 = proj_scale_d(pn0, kv, maxn);
    float sc = (tk0 / nnv0) * ps0;
    float xnr = pn0 * ps0;

    float s0f = (red[0][tid][0] + red[0][tid][1] + red[0][tid][2] + red[0][tid][3]) * sc * sc;
    float s1f = (red[1][tid][0] + red[1][tid][1] + red[1][tid][2] + red[1][tid][3]) * fabsf(sc);
    float s2f = (red[2][tid][0] + red[2][tid][1] + red[2][tid][2] + red[2][tid][3]) * sc;
    float xn = fmaxf(xnr, 1e-15f);
    float mxraw = sqrtf(s0f);
    float mxv = fmaxf(mxraw, 1e-15f);
    float ar = artan_k_d(xn, kv, sk);
    float c1 = tan_k_d(mxv / xn * ar, kv, sk);
    float s = (s1f == 0.f) ? 0.f : c1 / mxv;
    float pn = fmaxf(fabsf(c1) * (mxraw / mxv), 1e-15f);
    float ps = (s1f == 0.f) ? 1.f : proj_scale_d(pn, kv, maxn);
    s *= ps;
    float x2 = (s * s) * s0f;
    float xy = s * s2f;
    float Aa = 1.f - 2.f * kv * xy - kv * y2;
    float Cc = 1.f + kv * x2;
    float den = fmaxf(1.f - 2.f * kv * xy + (kv * kv) * x2 * y2, 1e-15f);
    nAs[tid] = Aa * s / den * sc;
    nCs[tid] = Cc / den;
  }
  __syncthreads();

#pragma unroll
  for (int r = 0; r < 4; r++) {
    int idx = quad * 4 + r;
    float Asc = nAs[idx], Cs = nCs[idx];
    float t0 = 0.f;
#pragma unroll
    for (int j2 = 0; j2 < 2; j2++) {
      float v = fmaf(Asc, acc[j2][r], Cs * bpj[j2]);
      t0 = fmaf(v, v, t0);
    }
#pragma unroll
    for (int m = 1; m < 16; m <<= 1) t0 += __shfl_xor(t0, m, 64);
    if (col == 0) redT[idx][w] = t0;
  }
  __syncthreads();

  if (tid < 16) {
    float t0f = redT[tid][0] + redT[tid][1] + redT[tid][2] + redT[tid][3];
    float nraw = sqrtf(t0f);
    float ps2 = proj_scale_d(fmaxf(nraw, 1e-15f), kv, maxn);
    float nh = fmaxf(ps2 * nraw, 1e-15f);
    nL[tid] = artan_k_d(nh, kv, sk) / nh * ps2;
  }
  __syncthreads();

#pragma unroll
  for (int r = 0; r < 4; r++) {
    int idx = quad * 4 + r;
    int gnode = n0w + idx;
    if (gnode >= n) continue;
    float Asc = nAs[idx], Cs = nCs[idx], L = nL[idx];
    f16* trow = tout + (size_t)gnode * 512;
#pragma unroll
    for (int j2 = 0; j2 < 2; j2++) {
      float v = fmaf(Asc, acc[j2][r], Cs * bpj[j2]);
      int d = (jt0 + j2) * 16 + col;
      trow[(d >> 1) * 8 + ex * 2 + (d & 1)] = (f16)(L * v);
    }
  }
}

// ---------------- fused multi-expert + gate edge sweep (double-buffered) ----------------
// MODE 0: layer-1 experts -> agg1 (raw fp32) ; gate hidden (32-dim, m1) -> g1 relu
// MODE 1: layer-2 experts -> logmap0(expmap0) pooling into feats ;
//         gate out (128-dim f16 tg) -> relu pooling into hgate
// t row: 64 granules of f16x8 = {e0d0,e0d1,e1d0,e1d1,e2d0,e2d1,e3d0,e3d1} per dim pair.
template <int MODE>
__global__ __launch_bounds__(256) void k_aggF(
    const int2* __restrict__ esw, const int* __restrict__ off,
    const int* __restrict__ bnode, const int* __restrict__ bslot,
    const int* __restrict__ batch, const f16x8* __restrict__ t,
    const float* __restrict__ gm1, const f16x2* __restrict__ tg,
    float* __restrict__ agg1, float* __restrict__ aggc,
    float* __restrict__ g1, float* __restrict__ feats,
    const float* __restrict__ gbias, float* __restrict__ hgate,
    int etot, CurvPack cp) {
  int gw = blockIdx.x * 4 + (threadIdx.x >> 6);
  int lane = threadIdx.x & 63;
  int e0 = gw * CHUNK;
  if (e0 >= etot) return;
  int e1 = min(e0 + CHUNK, etot);
  int lane7 = lane & 7;
  int lane31 = lane & 31;
  int bnHead = bnode[gw];
  int slotA = bslot[gw];
  int slotB = ((gw + 1) * CHUNK < etot) ? bslot[gw + 1] : slotA;
  int cur = bnHead;
  int runStart = off[cur];
  int eend = off[cur + 1];
  float ax[4], ay[4], pax[4], pay[4];
#pragma unroll
  for (int e = 0; e < 4; e++) ax[e] = ay[e] = pax[e] = pay[e] = 0.f;
  float gx = 0.f, gy = 0.f, pgx = 0.f, pgy = 0.f;
  int bcur = (MODE == 1) ? batch[cur] : 0;
  float bbx, bby = 0.f;
  if (MODE == 0) {
    bbx = gbias[lane31];
  } else {
    float2 bb = ((const float2*)gbias)[lane];
    bbx = bb.x;
    bby = bb.y;
  }

  auto flushInterior = [&]() {
#pragma unroll
    for (int e = 0; e < 4; e++) {
      if (MODE == 0) {
        ((float2*)agg1)[(size_t)cur * 256 + e * 64 + lane] = make_float2(ax[e], ay[e]);
      } else {
        float n2 = wsum64(fmaf(ax[e], ax[e], ay[e] * ay[e]));
        if (n2 <= cp.thr2[e]) {
          pax[e] += ax[e];
          pay[e] += ay[e];
        } else {
          float nraw = sqrtf(n2);
          float nnv = fmaxf(nraw, 1e-15f);
          float tk = tan_k_d(nnv, cp.k[e], cp.sk[e]);
          float s = tk / nnv;
          float pn = fmaxf(fabsf(tk) * (nraw / nnv), 1e-15f);
          float ps = proj_scale_d(pn, cp.k[e], cp.mx[e]);
          s *= ps;
          float nh = fmaxf(pn * ps, 1e-15f);
          float sc = artan_k_d(nh, cp.k[e], cp.sk[e]) / nh * s;
          pax[e] = fmaf(sc, ax[e], pax[e]);
          pay[e] = fmaf(sc, ay[e], pay[e]);
        }
      }
    }
    if (MODE == 0) {
      if (lane < 32) g1[(size_t)cur * 32 + lane] = fmaxf(gx + bbx, 0.f);
    } else {
      pgx += fmaxf(gx + bbx, 0.f);
      pgy += fmaxf(gy + bby, 0.f);
    }
  };
  auto flushBoundary = [&]() {
    int slot = (cur == bnHead) ? slotA : slotB;
    float* dp = aggc + (size_t)slot * 640;
#pragma unroll
    for (int e = 0; e < 4; e++) {
      atomicAdd(dp + e * 128 + lane * 2, ax[e]);
      atomicAdd(dp + e * 128 + lane * 2 + 1, ay[e]);
    }
    if (MODE == 0) {
      if (lane < 32) atomicAdd(dp + 512 + lane, gx);
    } else {
      atomicAdd(dp + 512 + lane * 2, gx);
      atomicAdd(dp + 512 + lane * 2 + 1, gy);
    }
  };
  auto flushPool = [&]() {
#pragma unroll
    for (int e = 0; e < 4; e++) {
      float* fp = &feats[(size_t)bcur * 512 + e * 128 + lane * 2];
      atomicAdd(fp, pax[e]);
      atomicAdd(fp + 1, pay[e]);
    }
    float* hp = &hgate[(size_t)bcur * 128 + lane * 2];
    atomicAdd(hp, pgx);
    atomicAdd(hp + 1, pgy);
  };

  // Double-buffered pipeline. CHUNK%16==0 except last chunk (16 edges) -> nb even always.
  f16x8 rvA[8], rvB[8];
  float gfA[8], gfB[8];
  f16x2 ghA[8], ghB[8];

#define LOADM(JJ) esw[min((JJ) + lane7, etot - 1)]

#define ISSUE8(RV, GF, GH, MV)                                        \
  {                                                                   \
    _Pragma("unroll") for (int q = 0; q < 8; q++) {                   \
      int s = __builtin_amdgcn_readlane((MV).x, q);                   \
      RV[q] = t[(size_t)s * 64 + lane];                               \
      if (MODE == 0) GF[q] = gm1[(size_t)s * 32 + lane31];            \
      else GH[q] = tg[(size_t)s * 64 + lane];                         \
    }                                                                 \
  }

#define PROCESS8(RV, GF, GH, MV, JB)                                  \
  {                                                                   \
    _Pragma("unroll") for (int q = 0; q < 8; q++) {                   \
      if ((JB) + q == eend) {                                         \
        if (runStart >= e0) flushInterior(); else flushBoundary();    \
        _Pragma("unroll") for (int e = 0; e < 4; e++) ax[e] = ay[e] = 0.f; \
        gx = gy = 0.f;                                                \
        runStart = (JB) + q;                                          \
        cur++;                                                        \
        eend = off[cur + 1];                                          \
        if (MODE == 1) {                                              \
          int nbt = batch[cur];                                       \
          if (nbt != bcur) {                                          \
            flushPool();                                              \
            _Pragma("unroll") for (int e = 0; e < 4; e++) pax[e] = pay[e] = 0.f; \
            pgx = pgy = 0.f;                                          \
            bcur = nbt;                                               \
          }                                                           \
        }                                                             \
      }                                                               \
      float w = __int_as_float(__builtin_amdgcn_readlane((MV).y, q)); \
      _Pragma("unroll") for (int e = 0; e < 4; e++) {                 \
        ax[e] = fmaf(w, (float)RV[q][2 * e], ax[e]);                  \
        ay[e] = fmaf(w, (float)RV[q][2 * e + 1], ay[e]);              \
      }                                                               \
      if (MODE == 0) {                                                \
        gx = fmaf(w, GF[q], gx);                                      \
      } else {                                                        \
        gx = fmaf(w, (float)GH[q][0], gx);                            \
        gy = fmaf(w, (float)GH[q][1], gy);                            \
      }                                                               \
    }                                                                 \
  }

  int nb = (e1 - e0) >> 3;  // batches of 8; always even (CHUNK=64 or 16-edge tail)
  int2 mvA = LOADM(e0);
  int2 mvB = LOADM(e0 + 8);
  ISSUE8(rvA, gfA, ghA, mvA);

  int j = e0;
  for (int b = 0; b < nb; b += 2, j += 16) {
    int2 mvC = LOADM(j + 16);
    ISSUE8(rvB, gfB, ghB, mvB);          // rows for batch b+1 (mv long in flight)
    PROCESS8(rvA, gfA, ghA, mvA, j);     // consume batch b
    int2 mvD = LOADM(j + 24);
    if (b + 2 < nb) {
      ISSUE8(rvA, gfA, ghA, mvC);        // rows for batch b+2
    }
    PROCESS8(rvB, gfB, ghB, mvB, j + 8); // consume batch b+1
    mvA = mvC;
    mvB = mvD;
  }
  if (runStart >= e0 && eend <= e1) flushInterior(); else flushBoundary();
  if (MODE == 1) flushPool();

#undef LOADM
#undef ISSUE8
#undef PROCESS8
}

// ---------------- fixups for chunk-spanning runs ----------------
__global__ void k_fix1(const int* __restrict__ bnode, const int* __restrict__ bslot,
                       const int* __restrict__ off, const float* __restrict__ aggc,
                       float* __restrict__ agg1, float* __restrict__ g1,
                       const float* __restrict__ gb1, int nchunk) {
  int g = blockIdx.x * 4 + (threadIdx.x >> 6);
  int lane = threadIdx.x & 63;
  if (g >= nchunk) return;
  int nd;
  if (!span_head(bnode, bslot, off, g, nd)) return;
  const float* sp = aggc + (size_t)g * 640;
#pragma unroll
  for (int e = 0; e < 4; e++) {
    float2 v = ((const float2*)sp)[e * 64 + lane];
    ((float2*)agg1)[(size_t)nd * 256 + e * 64 + lane] = v;
  }
  if (lane < 32) g1[(size_t)nd * 32 + lane] = fmaxf(sp[512 + lane] + gb1[lane], 0.f);
}

__global__ void k_fix2(const int* __restrict__ bnode, const int* __restrict__ bslot,
                       const int* __restrict__ off, const float* __restrict__ aggc,
                       const int* __restrict__ batch, float* __restrict__ feats,
                       const float* __restrict__ gb2, float* __restrict__ hgate,
                       int nchunk, CurvPack cp) {
  int g = blockIdx.x * 4 + (threadIdx.x >> 6);
  int lane = threadIdx.x & 63;
  if (g >= nchunk) return;
  int nd;
  if (!span_head(bnode, bslot, off, g, nd)) return;
  int b = batch[nd];
  const float* sp = aggc + (size_t)g * 640;
#pragma unroll
  for (int e = 0; e < 4; e++) {
    float2 v = ((const float2*)sp)[e * 64 + lane];
    float n2 = wsum64(fmaf(v.x, v.x, v.y * v.y));
    float nraw = sqrtf(n2);
    float nnv = fmaxf(nraw, 1e-15f);
    float tk = tan_k_d(nnv, cp.k[e], cp.sk[e]);
    float s = tk / nnv;
    float pn = fmaxf(fabsf(tk) * (nraw / nnv), 1e-15f);
    float ps = proj_scale_d(pn, cp.k[e], cp.mx[e]);
    s *= ps;
    float nh = fmaxf(pn * ps, 1e-15f);
    float sc = artan_k_d(nh, cp.k[e], cp.sk[e]) / nh * s;
    float* fp = &feats[(size_t)b * 512 + e * 128 + lane * 2];
    atomicAdd(fp, sc * v.x);
    atomicAdd(fp + 1, sc * v.y);
  }
  float2 gv = ((const float2*)(sp + 512))[lane];
  float2 bb = ((const float2*)gb2)[lane];
  float* hp = &hgate[(size_t)b * 128 + lane * 2];
  atomicAdd(hp, fmaxf(gv.x + bb.x, 0.f));
  atomicAdd(hp + 1, fmaxf(gv.y + bb.y, 0.f));
}

// ---------------- gate GEMM 1 ----------------
__global__ __launch_bounds__(256) void k_gate1(const float* __restrict__ x,
                                               const float* __restrict__ gw1,
                                               float* __restrict__ m1, int n) {
  __shared__ float xT[64][68];
  __shared__ float Wt[64][36];
  int tid = threadIdx.x;
  int n0 = blockIdx.x * 64;
  int c = tid & 7, r = tid >> 3;
  float acc[2][4];
#pragma unroll
  for (int i = 0; i < 2; i++)
#pragma unroll
    for (int jj = 0; jj < 4; jj++) acc[i][jj] = 0.f;

  for (int kc = 0; kc < 2; kc++) {
    if (kc) __syncthreads();
#pragma unroll
    for (int it = 0; it < 8; it++) {
      int u = tid + it * 256;
      int j = u >> 6, kd = u & 63;
      Wt[kd][j] = gw1[j * 128 + kc * 64 + kd];
    }
#pragma unroll
    for (int it = 0; it < 4; it++) {
      int u = tid + it * 256;
      int node = u >> 4, c4 = u & 15;
      float4 v = make_float4(0.f, 0.f, 0.f, 0.f);
      if (n0 + node < n) v = ((const float4*)x)[(size_t)(n0 + node) * 32 + kc * 16 + c4];
      xT[4 * c4 + 0][node] = v.x;
      xT[4 * c4 + 1][node] = v.y;
      xT[4 * c4 + 2][node] = v.z;
      xT[4 * c4 + 3][node] = v.w;
    }
    __syncthreads();
#pragma unroll 8
    for (int kd = 0; kd < 64; kd++) {
      float2 av = *(const float2*)&xT[kd][r * 2];
      float4 bv = *(const float4*)&Wt[kd][c * 4];
      float a[2] = {av.x, av.y};
      float bbv[4] = {bv.x, bv.y, bv.z, bv.w};
#pragma unroll
      for (int i = 0; i < 2; i++)
#pragma unroll
        for (int jj = 0; jj < 4; jj++) acc[i][jj] = fmaf(a[i], bbv[jj], acc[i][jj]);
    }
  }
#pragma unroll
  for (int i = 0; i < 2; i++) {
    int node = n0 + r * 2 + i;
    if (node >= n) continue;
    ((float4*)m1)[(size_t)node * 8 + c] = make_float4(acc[i][0], acc[i][1], acc[i][2], acc[i][3]);
  }
}

// ---------------- gate GEMM 2 (fp16 out, contiguous rows of 128 halfs) ----------------
__global__ __launch_bounds__(256) void k_gate2(const float* __restrict__ g1,
                                               const float* __restrict__ gw2,
                                               f16* __restrict__ m2, int n) {
  __shared__ float xT[32][68];
  __shared__ float Wt[32][132];
  int tid = threadIdx.x;
  int n0 = blockIdx.x * 64;
  int c = tid & 15, r = tid >> 4;
  float acc[4][8];
#pragma unroll
  for (int i = 0; i < 4; i++)
#pragma unroll
    for (int jj = 0; jj < 8; jj++) acc[i][jj] = 0.f;

#pragma unroll
  for (int it = 0; it < 16; it++) {
    int u = tid + it * 256;
    int j = u >> 5, kd = u & 31;
    Wt[kd][j] = gw2[j * 32 + kd];
  }
#pragma unroll
  for (int it = 0; it < 2; it++) {
    int u = tid + it * 256;
    int node = u >> 3, c4 = u & 7;
    float4 v = make_float4(0.f, 0.f, 0.f, 0.f);
    if (n0 + node < n) v = ((const float4*)g1)[(size_t)(n0 + node) * 8 + c4];
    xT[4 * c4 + 0][node] = v.x;
    xT[4 * c4 + 1][node] = v.y;
    xT[4 * c4 + 2][node] = v.z;
    xT[4 * c4 + 3][node] = v.w;
  }
  __syncthreads();
#pragma unroll 8
  for (int kd = 0; kd < 32; kd++) {
    float4 av = *(const float4*)&xT[kd][r * 4];
    float4 b0 = *(const float4*)&Wt[kd][c * 8];
    float4 b1 = *(const float4*)&Wt[kd][c * 8 + 4];
    float a[4] = {av.x, av.y, av.z, av.w};
    float bbv[8] = {b0.x, b0.y, b0.z, b0.w, b1.x, b1.y, b1.z, b1.w};
#pragma unroll
    for (int i = 0; i < 4; i++)
#pragma unroll
      for (int jj = 0; jj < 8; jj++) acc[i][jj] = fmaf(a[i], bbv[jj], acc[i][jj]);
  }
#pragma unroll
  for (int i = 0; i < 4; i++) {
    int node = n0 + r * 4 + i;
    if (node >= n) continue;
    f16x8 hv;
#pragma unroll
    for (int jj = 0; jj < 8; jj++) hv[jj] = (f16)acc[i][jj];
    *((f16x8*)(m2 + (size_t)node * 128) + c) = hv;
  }
}

// ---------------- final ----------------
__global__ __launch_bounds__(128) void k_final(const float* __restrict__ feats,
                                               const float* __restrict__ hgate,
                                               const float* __restrict__ counts,
                                               const float* __restrict__ gate_u,
                                               const float* __restrict__ tau_raw,
                                               float* __restrict__ out, CurvPack cp) {
  __shared__ float l2[2];
  int b = blockIdx.x;
  int j = threadIdx.x;
  float cnt = fmaxf(counts[b], 1.f);
  float hg = hgate[(size_t)b * 128 + j] / cnt;

  auto bsum = [&](float v) -> float {
    v = wsum64(v);
    __syncthreads();
    if ((j & 63) == 0) l2[j >> 6] = v;
    __syncthreads();
    return l2[0] + l2[1];
  };

  float nhg2 = bsum(hg * hg);
  float nhgraw = sqrtf(nhg2);
  float nhg = fmaxf(nhgraw, 1e-15f);

  float d[4], tau[4];
#pragma unroll
  for (int i = 0; i < 4; i++) {
    float kv = cp.k[i], sk = cp.sk[i], mxn = cp.mx[i];
    float tk = tan_k_d(nhg, kv, sk);
    float s = tk / nhg;
    float pn = fmaxf(fabsf(tk) * (nhgraw / nhg), 1e-15f);
    s *= proj_scale_d(pn, kv, mxn);
    float zk = s * hg;

    float u = gate_u[i * 128 + j];
    float nu2 = bsum(u * u);
    float nuraw = sqrtf(nu2);
    float nu = fmaxf(nuraw, 1e-15f);
    float tku = tan_k_d(nu, kv, sk);
    float su = tku / nu;
    float pnu = fmaxf(fabsf(tku) * (nuraw / nu), 1e-15f);
    su *= proj_scale_d(pnu, kv, mxn);
    float yk = su * u;

    float xv = -zk;
    float x2 = bsum(xv * xv);
    float y2 = bsum(yk * yk);
    float xy = bsum(xv * yk);
    float A = 1.f - 2.f * kv * xy - kv * y2;
    float C = 1.f + kv * x2;
    float den = fmaxf(1.f - 2.f * kv * xy + (kv * kv) * x2 * y2, 1e-15f);
    float ma = (A * xv + C * yk) / den;
    float m2 = bsum(ma * ma);
    float mraw = sqrtf(m2);
    float ps2 = proj_scale_d(fmaxf(mraw, 1e-15f), kv, mxn);
    float nm = fmaxf(ps2 * mraw, 1e-15f);
    d[i] = 2.f * artan_k_d(nm, kv, sk);

    float tr = tau_raw[i];
    tau[i] = fminf(fmaxf(log1pf(expf(tr)) + 0.05f, 0.05f), 10.f);
  }

  float xi[4];
  float mxv = -1e30f;
#pragma unroll
  for (int i = 0; i < 4; i++) {
    xi[i] = -d[i] / tau[i];
    mxv = fmaxf(mxv, xi[i]);
  }
  float es = 0.f, e[4];
#pragma unroll
  for (int i = 0; i < 4; i++) {
    e[i] = expf(xi[i] - mxv);
    es += e[i];
  }
  float w[4];
#pragma unroll
  for (int i = 0; i < 4; i++) w[i] = e[i] / es;

#pragma unroll
  for (int i = 0; i < 4; i++)
    out[(size_t)b * 512 + i * 128 + j] = feats[(size_t)b * 512 + i * 128 + j] / cnt * w[i];

  if (j < 4) {
    out[65536 + b * 4 + j] = w[j];
    out[66048 + b * 4 + j] = d[j];
  }
  if (b == 0 && j < 4) out[66560 + j] = tau[j];
}

// ---------------- host launcher ----------------
extern "C" void kernel_launch(void* const* d_in, const int* in_sizes, int n_in,
                              void* d_out, int out_size, void* d_ws, size_t ws_size,
                              hipStream_t stream) {
  const float* x = (const float*)d_in[0];
  const int* ei = (const int*)d_in[1];
  const int* batch = (const int*)d_in[2];
  const float* ew1 = (const float*)d_in[3];
  const float* eb1 = (const float*)d_in[4];
  const float* ew2 = (const float*)d_in[5];
  const float* eb2 = (const float*)d_in[6];
  const float* gw1 = (const float*)d_in[7];
  const float* gb1 = (const float*)d_in[8];
  const float* gw2 = (const float*)d_in[9];
  const float* gb2 = (const float*)d_in[10];
  const float* gu = (const float*)d_in[11];
  const float* traw = (const float*)d_in[12];
  float* out = (float*)d_out;

  const int N = NN, E = EE, ET = ETOT, B = BB;

  float* ws = (float*)d_ws;
  size_t o = 0;
  f16* t4 = (f16*)ws;       o += (size_t)N * 256;   // N*512 halfs, granule-interleaved
  float* agg1 = ws + o;     o += (size_t)N * 512;   // layer-1 raw agg, [node][ex*128+d]
  float* aggc = ws + o;     o += (size_t)NCHUNK * 640;  // boundary accum (512 exp + 128 gate)
  float* deg = ws + o;      o += N;                 // becomes dinv
  float* counts = ws + o;   o += 256;
  float* feats = ws + o;    o += (size_t)B * 512;
  float* hg = ws + o;       o += (size_t)B * 128;
  float* biasb = ws + o;    o += 8 * 132;
  f16* whi = (f16*)(ws + o);    o += 8 * 16384 / 2;
  f16* wlo = (f16*)(ws + o);    o += 8 * 16384 / 2;
  float* m1 = ws + o;       o += (size_t)N * 32;    // gate hidden pre-agg
  float* g1 = ws + o;       o += (size_t)N * 32;    // gate hidden post-relu
  f16* tg = (f16*)(ws + o); o += (size_t)N * 64;    // gate out f16, [node][128]
  int* ideg = (int*)(ws + o);   o += N;
  int* csroff = (int*)(ws + o); o += N + 8;
  int* cursor = (int*)(ws + o); o += N;
  int* boff = (int*)(ws + o);   o += 136;
  int* bsum = (int*)(ws + o);   o += 256;
  int* bnode = (int*)(ws + o);  o += NCHUNK + 8;
  int* bslot = (int*)(ws + o);  o += NCHUNK + 8;
  int2* esw = (int2*)(ws + o);  o += (size_t)2 * ET;

  hipMemsetAsync(counts, 0, (256 + (size_t)B * 512 + (size_t)B * 128) * sizeof(float), stream);

  const double curvs[4] = {-1.0, 0.0, 1.0, -0.5};
  CurvPack cp;
  for (int i = 0; i < 4; i++) {
    double kd = curvs[i];
    double skd = sqrt(fabs(kd));
    cp.k[i] = (float)kd;
    cp.sk[i] = (float)skd;
    cp.mx[i] = (kd < 0) ? (float)((1.0 - 1e-5) / skd) : 3.0e38f;
    // fast-path threshold: |agg| below this => logmap0(expmap0(v)) == v
    if (kd < 0) {
      double thr = 6.0 / skd;  // tanh(6.0)=0.9999877 < 1-1e-5 => no clamp
      cp.thr2[i] = (float)(thr * thr);
    } else if (kd > 0) {
      double thr = 1.5 / skd;  // < pi/2 => no tan wrap
      cp.thr2[i] = (float)(thr * thr);
    } else {
      cp.thr2[i] = 3.0e38f;    // k=0: identity always
    }
  }

  k_init<<<(N + 255) / 256, 256, 0, stream>>>(deg, N);
  k_counts<<<1, 256, 0, stream>>>(batch, boff, counts, N);
  k_deg<<<(E + 255) / 256, 256, 0, stream>>>(ei, deg, E);
  k_dinv<<<(N + 255) / 256, 256, 0, stream>>>(deg, ideg, N);
  k_scanA<<<SCB, 256, 0, stream>>>(ideg, bsum, N);
  k_scanB<<<1, 256, 0, stream>>>(bsum, SCB);
  k_scanC<<<SCB, 256, 0, stream>>>(ideg, bsum, csroff, cursor, N);
  k_bnodes<<<(NCHUNK + 255) / 256, 256, 0, stream>>>(csroff, bnode, NCHUNK, N);
  k_bslot<<<(NCHUNK + 255) / 256, 256, 0, stream>>>(bnode, bslot, NCHUNK);
  k_place<<<(ET + 255) / 256, 256, 0, stream>>>(ei, deg, cursor, esw, E, N);
  k_biaspt_all<<<8, 128, 0, stream>>>(eb1, eb2, biasb, cp);
  k_w2h<<<512, 256, 0, stream>>>(ew1, ew2, whi, wlo);
  k_gate1<<<(N + 63) / 64, 256, 0, stream>>>(x, gw1, m1, N);

  const int aggBlocks = (NCHUNK + 3) / 4;
  dim3 mfmaGrid((N + 15) / 16, 4);

  // ---- layer 1 (all 4 experts fused) + gate hidden ----
  k_matmfma<<<mfmaGrid, 256, 0, stream>>>(x, 128, 0, whi, wlo, biasb, 0, t4, N, cp);
  k_zeroc<<<aggBlocks, 256, 0, stream>>>(bnode, bslot, csroff, aggc, NCHUNK);
  k_aggF<0><<<aggBlocks, 256, 0, stream>>>(esw, csroff, bnode, bslot, batch,
                                           (const f16x8*)t4, m1, nullptr, agg1, aggc, g1,
                                           nullptr, gb1, nullptr, ET, cp);
  k_fix1<<<aggBlocks, 256, 0, stream>>>(bnode, bslot, csroff, aggc, agg1, g1, gb1, NCHUNK);
  k_gate2<<<(N + 63) / 64, 256, 0, stream>>>(g1, gw2, tg, N);

  // ---- layer 2 + gate out pooling ----
  k_matmfma<<<mfmaGrid, 256, 0, stream>>>(agg1, 512, 128, whi, wlo, biasb, 1, t4, N, cp);
  k_zeroc<<<aggBlocks, 256, 0, stream>>>(bnode, bslot, csroff, aggc, NCHUNK);
  k_aggF<1><<<aggBlocks, 256, 0, stream>>>(esw, csroff, bnode, bslot, batch,
                                           (const f16x8*)t4, nullptr, (const f16x2*)tg,
                                           nullptr, aggc, nullptr, feats, gb2, hg, ET, cp);
  k_fix2<<<aggBlocks, 256, 0, stream>>>(bnode, bslot, csroff, aggc, batch, feats, gb2, hg,
                                        NCHUNK, cp);

  k_final<<<B, 128, 0, stream>>>(feats, hg, counts, gu, traw, out, cp);

  (void)in_sizes; (void)n_in; (void)out_size; (void)ws_size;
}

// Round 3
// 1068.714 us; speedup vs baseline: 1.0020x; 1.0020x over previous
//
#include <hip/hip_runtime.h>
#include <math.h>

// ---------------- constants ----------------
#define NN 50000
#define EE 800000
#define ETOT (EE + NN)
#define BB 128
#define DIM 128
#define GHID 32
#define CHUNK 64
#define NCHUNK ((ETOT + CHUNK - 1) / CHUNK)
#define SCB 196  // scan blocks: 196*256 >= 50000

typedef _Float16 f16;
typedef _Float16 f16x2 __attribute__((ext_vector_type(2)));
typedef _Float16 f16x8 __attribute__((ext_vector_type(8)));
typedef float f32x4 __attribute__((ext_vector_type(4)));

struct CurvPack {
  float k[4], sk[4], mx[4], thr2[4];
};

// ---------------- device math helpers ----------------
__device__ __forceinline__ float wsum64(float v) {
#pragma unroll
  for (int m = 32; m; m >>= 1) v += __shfl_xor(v, m, 64);
  return v;
}

__device__ __forceinline__ float tan_k_d(float x, float kv, float sk) {
  if (kv > 0.f) return tanf(x * sk) / sk;
  if (kv < 0.f) return tanhf(x * sk) / sk;
  return x;
}

__device__ __forceinline__ float artan_k_d(float x, float kv, float sk) {
  if (kv > 0.f) return atanf(x * sk) / sk;
  if (kv < 0.f) {
    float t = x * sk;
    t = fminf(fmaxf(t, -1.f + 1e-7f), 1.f - 1e-7f);
    return atanhf(t) / sk;
  }
  return x;
}

__device__ __forceinline__ float proj_scale_d(float n, float kv, float maxn) {
  if (kv < 0.f && n > maxn) return maxn / n;
  return 1.f;
}

// ---------------- graph preprocessing ----------------
__global__ void k_init(float* __restrict__ deg, int n) {
  int i = blockIdx.x * 256 + threadIdx.x;
  if (i < n) deg[i] = 1.0f;  // self loop
}

__global__ void k_counts(const int* __restrict__ batch, int* __restrict__ boff,
                         float* __restrict__ counts, int n) {
  int b = threadIdx.x;
  if (b <= 128) {
    int lo = 0, hi = n;
    while (lo < hi) {
      int mid = (lo + hi) >> 1;
      if (batch[mid] < b) lo = mid + 1; else hi = mid;
    }
    boff[b] = lo;
  }
  __syncthreads();
  if (b < 128) counts[b] = (float)(boff[b + 1] - boff[b]);
}

__global__ void k_deg(const int* __restrict__ ei, float* __restrict__ deg, int e) {
  int i = blockIdx.x * 256 + threadIdx.x;
  if (i < e) atomicAdd(&deg[ei[e + i]], 1.0f);
}

__global__ void k_dinv(float* __restrict__ deg, int* __restrict__ ideg, int n) {
  int i = blockIdx.x * 256 + threadIdx.x;
  if (i < n) {
    float d = deg[i];
    ideg[i] = (int)(d + 0.5f);
    deg[i] = 1.0f / sqrtf(d);
  }
}

// ---------------- parallel scan ----------------
__global__ void k_scanA(const int* __restrict__ ideg, int* __restrict__ bsum, int n) {
  __shared__ int ls[4];
  int i = blockIdx.x * 256 + threadIdx.x;
  int v = (i < n) ? ideg[i] : 0;
#pragma unroll
  for (int m = 1; m < 64; m <<= 1) v += __shfl_xor(v, m, 64);
  if ((threadIdx.x & 63) == 0) ls[threadIdx.x >> 6] = v;
  __syncthreads();
  if (threadIdx.x == 0) bsum[blockIdx.x] = ls[0] + ls[1] + ls[2] + ls[3];
}

__global__ void k_scanB(int* __restrict__ bsum, int nb) {
  __shared__ int wsh[4];
  int tid = threadIdx.x;
  int lane = tid & 63, w = tid >> 6;
  int v = (tid < nb) ? bsum[tid] : 0;
  int x = v;
#pragma unroll
  for (int o = 1; o < 64; o <<= 1) {
    int t = __shfl_up(x, o, 64);
    if (lane >= o) x += t;
  }
  if (lane == 63) wsh[w] = x;
  __syncthreads();
  int add = 0;
  for (int k2 = 0; k2 < w; k2++) add += wsh[k2];
  if (tid < nb) bsum[tid] = add + x - v;
}

__global__ void k_scanC(const int* __restrict__ ideg, const int* __restrict__ bsum,
                        int* __restrict__ off, int* __restrict__ cursor, int n) {
  __shared__ int wsh[4];
  int i = blockIdx.x * 256 + threadIdx.x;
  int lane = threadIdx.x & 63, w = threadIdx.x >> 6;
  int v = (i < n) ? ideg[i] : 0;
  int x = v;
#pragma unroll
  for (int o = 1; o < 64; o <<= 1) {
    int t = __shfl_up(x, o, 64);
    if (lane >= o) x += t;
  }
  if (lane == 63) wsh[w] = x;
  __syncthreads();
  int add = bsum[blockIdx.x];
  for (int k2 = 0; k2 < w; k2++) add += wsh[k2];
  int excl = add + x - v;
  if (i < n) {
    off[i] = excl;
    cursor[i] = excl;
  }
  if (i == n - 1) off[n] = excl + v;
}

// ---------------- chunk head nodes + first-occurrence slots ----------------
__global__ void k_bnodes(const int* __restrict__ off, int* __restrict__ bnode, int nchunk,
                         int n) {
  int g = blockIdx.x * 256 + threadIdx.x;
  if (g >= nchunk) return;
  int e0 = g * CHUNK;
  int lo = 0, hi = n;
  while (hi - lo > 1) {
    int mid = (lo + hi) >> 1;
    if (off[mid] <= e0) lo = mid; else hi = mid;
  }
  bnode[g] = lo;
}

__global__ void k_bslot(const int* __restrict__ bnode, int* __restrict__ bslot, int nchunk) {
  int g = blockIdx.x * 256 + threadIdx.x;
  if (g >= nchunk) return;
  int v = bnode[g];
  int lo = 0, hi = g;
  while (lo < hi) {
    int mid = (lo + hi) >> 1;
    if (bnode[mid] < v) lo = mid + 1; else hi = mid;
  }
  bslot[g] = lo;
}

__device__ __forceinline__ bool span_head(const int* bnode, const int* bslot, const int* off,
                                          int g, int& nd) {
  if (bslot[g] != g) return false;
  nd = bnode[g];
  int s = off[nd], e = off[nd + 1];
  return (s / CHUNK) != ((e - 1) / CHUNK);
}

// zero spanning boundary slots of aggc (640 floats per slot)
__global__ void k_zeroc(const int* __restrict__ bnode, const int* __restrict__ bslot,
                        const int* __restrict__ off, float* __restrict__ aggc, int nchunk) {
  int g = blockIdx.x * 4 + (threadIdx.x >> 6);
  int lane = threadIdx.x & 63;
  if (g >= nchunk) return;
  int nd;
  if (!span_head(bnode, bslot, off, g, nd)) return;
  float2 z = make_float2(0.f, 0.f);
#pragma unroll
  for (int i = 0; i < 5; i++) ((float2*)aggc)[(size_t)g * 320 + i * 64 + lane] = z;
}

// ---------------- edge placement ----------------
__global__ void k_place(const int* __restrict__ ei, const float* __restrict__ dinv,
                        int* __restrict__ cursor, int2* __restrict__ esw, int e, int n) {
  int i = blockIdx.x * 256 + threadIdx.x;
  int et = e + n;
  if (i >= et) return;
  int r_, c_;
  if (i < e) {
    r_ = ei[i];
    c_ = ei[e + i];
  } else {
    r_ = i - e;
    c_ = i - e;
  }
  int p = atomicAdd(&cursor[c_], 1);
  esw[p] = make_int2(r_, __float_as_int(dinv[r_] * dinv[c_]));
}

// ---------------- bias points ----------------
__global__ void k_biaspt_all(const float* __restrict__ eb1, const float* __restrict__ eb2,
                             float* __restrict__ biasb, CurvPack cp) {
  __shared__ float l2[2];
  int blk = blockIdx.x;  // ex*2 + layer
  int ex = blk >> 1, layer = blk & 1;
  float kv = cp.k[ex], sk = cp.sk[ex], maxn = cp.mx[ex];
  const float* b = (layer ? eb2 : eb1) + ex * 128;
  float* outb = biasb + blk * 132;
  int j = threadIdx.x;
  float v = b[j];
  float n2 = wsum64(v * v);
  if ((j & 63) == 0) l2[j >> 6] = n2;
  __syncthreads();
  n2 = l2[0] + l2[1];
  float nraw = sqrtf(n2);
  float nnv = fmaxf(nraw, 1e-15f);
  float tk = tan_k_d(nnv, kv, sk);
  float s = tk / nnv;
  float pn = fmaxf(fabsf(tk) * (nraw / nnv), 1e-15f);
  float ps = proj_scale_d(pn, kv, maxn);
  float bp = ps * s * v;
  outb[j] = bp;
  float y2v = wsum64(bp * bp);
  __syncthreads();
  if ((j & 63) == 0) l2[j >> 6] = y2v;
  __syncthreads();
  if (j == 0) outb[128] = l2[0] + l2[1];
}

// ---------------- W -> fp16 hi/lo split ----------------
__global__ void k_w2h(const float* __restrict__ ew1, const float* __restrict__ ew2,
                      f16* __restrict__ whi, f16* __restrict__ wlo) {
  int i = blockIdx.x * 256 + threadIdx.x;
  if (i >= 8 * 16384) return;
  int slot = i >> 14;
  int r = i & 16383;
  int ex = slot >> 1, layer = slot & 1;
  float w = (layer ? ew2 : ew1)[ex * 16384 + r];
  f16 h = (f16)w;
  whi[i] = h;
  wlo[i] = (f16)(w - (float)h);
}

// ---------------- MFMA expert GEMM (fp32 A split in-kernel; A-row norm fused) -------
// grid.y = expert. Output t interleaved: half offset (d>>1)*8 + ex*2 + (d&1).
__global__ __launch_bounds__(256) void k_matmfma(
    const float* __restrict__ A, int astr, int aoffPerEx,
    const f16* __restrict__ whiB, const f16* __restrict__ wloB,
    const float* __restrict__ biasB, int layer, f16* __restrict__ tout, int n,
    CurvPack cp) {
  __shared__ float red[3][16][4];
  __shared__ float redT[16][4];
  __shared__ float nAs[16], nCs[16], nL[16];
  int ex = blockIdx.y;
  float kv = cp.k[ex], sk = cp.sk[ex], maxn = cp.mx[ex];
  const f16* whi = whiB + (size_t)(ex * 2 + layer) * 16384;
  const f16* wlo = wloB + (size_t)(ex * 2 + layer) * 16384;
  const float* biasb = biasB + (ex * 2 + layer) * 132;

  int tid = threadIdx.x;
  int w = tid >> 6;
  int lane = tid & 63;
  int col = lane & 15;
  int quad = lane >> 4;
  int n0w = blockIdx.x * 16;
  if (n0w >= n) return;

  int anodec = min(n0w + col, n - 1);
  const float* arow = A + (size_t)anodec * astr + ex * aoffPerEx;
  int jt0 = w * 2;

  f32x4 acc[2];
  acc[0] = (f32x4){0.f, 0.f, 0.f, 0.f};
  acc[1] = (f32x4){0.f, 0.f, 0.f, 0.f};
  float a_n2 = 0.f;

#pragma unroll
  for (int kc = 0; kc < 4; kc++) {
    int kb = kc * 32 + quad * 8;
    float4 a0 = *(const float4*)(arow + kb);
    float4 a1 = *(const float4*)(arow + kb + 4);
    float av[8] = {a0.x, a0.y, a0.z, a0.w, a1.x, a1.y, a1.z, a1.w};
    f16x8 Ah, Al;
#pragma unroll
    for (int i = 0; i < 8; i++) {
      a_n2 = fmaf(av[i], av[i], a_n2);
      f16 h = (f16)av[i];
      Ah[i] = h;
      Al[i] = (f16)(av[i] - (float)h);
    }
#pragma unroll
    for (int j2 = 0; j2 < 2; j2++) {
      const f16* bh = whi + (size_t)((jt0 + j2) * 16 + col) * 128 + kb;
      const f16* bl = wlo + (size_t)((jt0 + j2) * 16 + col) * 128 + kb;
      f16x8 Bh = *(const f16x8*)bh;
      f16x8 Bl = *(const f16x8*)bl;
      acc[j2] = __builtin_amdgcn_mfma_f32_16x16x32_f16(Ah, Bh, acc[j2], 0, 0, 0);
      acc[j2] = __builtin_amdgcn_mfma_f32_16x16x32_f16(Ah, Bl, acc[j2], 0, 0, 0);
      acc[j2] = __builtin_amdgcn_mfma_f32_16x16x32_f16(Al, Bh, acc[j2], 0, 0, 0);
    }
  }
  // reduce per-quad partial norms across quads (per col)
  a_n2 += __shfl_xor(a_n2, 16, 64);
  a_n2 += __shfl_xor(a_n2, 32, 64);

  float bpj[2];
  bpj[0] = biasb[jt0 * 16 + col];
  bpj[1] = biasb[(jt0 + 1) * 16 + col];
  float y2 = biasb[128];

#pragma unroll
  for (int r = 0; r < 4; r++) {
    float s0 = 0.f, s1 = 0.f, s2 = 0.f;
#pragma unroll
    for (int j2 = 0; j2 < 2; j2++) {
      float v = acc[j2][r];
      s0 = fmaf(v, v, s0);
      s1 += fabsf(v);
      s2 = fmaf(v, bpj[j2], s2);
    }
#pragma unroll
    for (int m = 1; m < 16; m <<= 1) {
      s0 += __shfl_xor(s0, m, 64);
      s1 += __shfl_xor(s1, m, 64);
      s2 += __shfl_xor(s2, m, 64);
    }
    if (col == 0) {
      red[0][quad * 4 + r][w] = s0;
      red[1][quad * 4 + r][w] = s1;
      red[2][quad * 4 + r][w] = s2;
    }
  }
  __syncthreads();

  if (tid < 16) {
    // expmap0 scale from the A-row norm (was k_nodeprep / MODE0-flush)
    float nraw0 = sqrtf(a_n2);
    float nnv0 = fmaxf(nraw0, 1e-15f);
    float tk0 = tan_k_d(nnv0, kv, sk);
    float pn0 = fmaxf(fabsf(tk0) * (nraw0 / nnv0), 1e-15f);
    float ps0 = proj_scale_d(pn0, kv, maxn);
    float sc = (tk0 / nnv0) * ps0;
    float xnr = pn0 * ps0;

    float s0f = (red[0][tid][0] + red[0][tid][1] + red[0][tid][2] + red[0][tid][3]) * sc * sc;
    float s1f = (red[1][tid][0] + red[1][tid][1] + red[1][tid][2] + red[1][tid][3]) * fabsf(sc);
    float s2f = (red[2][tid][0] + red[2][tid][1] + red[2][tid][2] + red[2][tid][3]) * sc;
    float xn = fmaxf(xnr, 1e-15f);
    float mxraw = sqrtf(s0f);
    float mxv = fmaxf(mxraw, 1e-15f);
    float ar = artan_k_d(xn, kv, sk);
    float c1 = tan_k_d(mxv / xn * ar, kv, sk);
    float s = (s1f == 0.f) ? 0.f : c1 / mxv;
    float pn = fmaxf(fabsf(c1) * (mxraw / mxv), 1e-15f);
    float ps = (s1f == 0.f) ? 1.f : proj_scale_d(pn, kv, maxn);
    s *= ps;
    float x2 = (s * s) * s0f;
    float xy = s * s2f;
    float Aa = 1.f - 2.f * kv * xy - kv * y2;
    float Cc = 1.f + kv * x2;
    float den = fmaxf(1.f - 2.f * kv * xy + (kv * kv) * x2 * y2, 1e-15f);
    nAs[tid] = Aa * s / den * sc;
    nCs[tid] = Cc / den;
  }
  __syncthreads();

#pragma unroll
  for (int r = 0; r < 4; r++) {
    int idx = quad * 4 + r;
    float Asc = nAs[idx], Cs = nCs[idx];
    float t0 = 0.f;
#pragma unroll
    for (int j2 = 0; j2 < 2; j2++) {
      float v = fmaf(Asc, acc[j2][r], Cs * bpj[j2]);
      t0 = fmaf(v, v, t0);
    }
#pragma unroll
    for (int m = 1; m < 16; m <<= 1) t0 += __shfl_xor(t0, m, 64);
    if (col == 0) redT[idx][w] = t0;
  }
  __syncthreads();

  if (tid < 16) {
    float t0f = redT[tid][0] + redT[tid][1] + redT[tid][2] + redT[tid][3];
    float nraw = sqrtf(t0f);
    float ps2 = proj_scale_d(fmaxf(nraw, 1e-15f), kv, maxn);
    float nh = fmaxf(ps2 * nraw, 1e-15f);
    nL[tid] = artan_k_d(nh, kv, sk) / nh * ps2;
  }
  __syncthreads();

#pragma unroll
  for (int r = 0; r < 4; r++) {
    int idx = quad * 4 + r;
    int gnode = n0w + idx;
    if (gnode >= n) continue;
    float Asc = nAs[idx], Cs = nCs[idx], L = nL[idx];
    f16* trow = tout + (size_t)gnode * 512;
#pragma unroll
    for (int j2 = 0; j2 < 2; j2++) {
      float v = fmaf(Asc, acc[j2][r], Cs * bpj[j2]);
      int d = (jt0 + j2) * 16 + col;
      trow[(d >> 1) * 8 + ex * 2 + (d & 1)] = (f16)(L * v);
    }
  }
}

// ---------------- fused multi-expert + gate edge sweep ----------------
// MODE 0: layer-1 experts -> agg1 (raw fp32) ; gate hidden (32-dim, m1) -> g1 relu
// MODE 1: layer-2 experts -> logmap0(expmap0) pooling into feats ;
//         gate out (128-dim f16 tg) -> relu pooling into hgate
// t row: 64 granules of f16x8 = {e0d0,e0d1,e1d0,e1d1,e2d0,e2d1,e3d0,e3d1} per dim pair.
// CHUNK=64: whole-chunk metadata in ONE int2/lane load; batch loop fully unrolled so
// every readlane index is a compile-time constant (no per-batch metadata latency).
template <int MODE>
__global__ __launch_bounds__(256) void k_aggF(
    const int2* __restrict__ esw, const int* __restrict__ off,
    const int* __restrict__ bnode, const int* __restrict__ bslot,
    const int* __restrict__ batch, const f16x8* __restrict__ t,
    const float* __restrict__ gm1, const f16x2* __restrict__ tg,
    float* __restrict__ agg1, float* __restrict__ aggc,
    float* __restrict__ g1, float* __restrict__ feats,
    const float* __restrict__ gbias, float* __restrict__ hgate,
    int etot, CurvPack cp) {
  int gw = blockIdx.x * 4 + (threadIdx.x >> 6);
  int lane = threadIdx.x & 63;
  int e0 = gw * CHUNK;
  if (e0 >= etot) return;
  int e1 = min(e0 + CHUNK, etot);
  int lane31 = lane & 31;
  int bnHead = bnode[gw];
  int slotA = bslot[gw];
  int slotB = ((gw + 1) * CHUNK < etot) ? bslot[gw + 1] : slotA;
  int cur = bnHead;
  int runStart = off[cur];
  int eend = off[cur + 1];

  // whole-chunk edge metadata: lane l holds edge e0+l
  int2 mv = esw[min(e0 + lane, etot - 1)];

  float ax[4], ay[4], pax[4], pay[4];
#pragma unroll
  for (int e = 0; e < 4; e++) ax[e] = ay[e] = pax[e] = pay[e] = 0.f;
  float gx = 0.f, gy = 0.f, pgx = 0.f, pgy = 0.f;
  int bcur = (MODE == 1) ? batch[cur] : 0;
  float bbx, bby = 0.f;
  if (MODE == 0) {
    bbx = gbias[lane31];
  } else {
    float2 bb = ((const float2*)gbias)[lane];
    bbx = bb.x;
    bby = bb.y;
  }

  auto flushInterior = [&]() {
#pragma unroll
    for (int e = 0; e < 4; e++) {
      if (MODE == 0) {
        ((float2*)agg1)[(size_t)cur * 256 + e * 64 + lane] = make_float2(ax[e], ay[e]);
      } else {
        float n2 = wsum64(fmaf(ax[e], ax[e], ay[e] * ay[e]));
        if (n2 <= cp.thr2[e]) {
          pax[e] += ax[e];
          pay[e] += ay[e];
        } else {
          float nraw = sqrtf(n2);
          float nnv = fmaxf(nraw, 1e-15f);
          float tk = tan_k_d(nnv, cp.k[e], cp.sk[e]);
          float s = tk / nnv;
          float pn = fmaxf(fabsf(tk) * (nraw / nnv), 1e-15f);
          float ps = proj_scale_d(pn, cp.k[e], cp.mx[e]);
          s *= ps;
          float nh = fmaxf(pn * ps, 1e-15f);
          float sc = artan_k_d(nh, cp.k[e], cp.sk[e]) / nh * s;
          pax[e] = fmaf(sc, ax[e], pax[e]);
          pay[e] = fmaf(sc, ay[e], pay[e]);
        }
      }
    }
    if (MODE == 0) {
      if (lane < 32) g1[(size_t)cur * 32 + lane] = fmaxf(gx + bbx, 0.f);
    } else {
      pgx += fmaxf(gx + bbx, 0.f);
      pgy += fmaxf(gy + bby, 0.f);
    }
  };
  auto flushBoundary = [&]() {
    int slot = (cur == bnHead) ? slotA : slotB;
    float* dp = aggc + (size_t)slot * 640;
#pragma unroll
    for (int e = 0; e < 4; e++) {
      atomicAdd(dp + e * 128 + lane * 2, ax[e]);
      atomicAdd(dp + e * 128 + lane * 2 + 1, ay[e]);
    }
    if (MODE == 0) {
      if (lane < 32) atomicAdd(dp + 512 + lane, gx);
    } else {
      atomicAdd(dp + 512 + lane * 2, gx);
      atomicAdd(dp + 512 + lane * 2 + 1, gy);
    }
  };
  auto flushPool = [&]() {
#pragma unroll
    for (int e = 0; e < 4; e++) {
      float* fp = &feats[(size_t)bcur * 512 + e * 128 + lane * 2];
      atomicAdd(fp, pax[e]);
      atomicAdd(fp + 1, pay[e]);
    }
    float* hp = &hgate[(size_t)bcur * 128 + lane * 2];
    atomicAdd(hp, pgx);
    atomicAdd(hp + 1, pgy);
  };

  f16x8 rv[8];
  float gf[8];
  f16x2 gh[8];

#pragma unroll
  for (int b = 0; b < CHUNK / 8; b++) {
    int jb = e0 + b * 8;
    if (jb < e1) {
      // issue all 16 row loads for this batch (addresses from registers, no mem dep)
#pragma unroll
      for (int q = 0; q < 8; q++) {
        int s = __builtin_amdgcn_readlane(mv.x, b * 8 + q);
        rv[q] = t[(size_t)s * 64 + lane];
        if (MODE == 0) gf[q] = gm1[(size_t)s * 32 + lane31];
        else gh[q] = tg[(size_t)s * 64 + lane];
      }
      // consume
#pragma unroll
      for (int q = 0; q < 8; q++) {
        if (jb + q == eend) {
          if (runStart >= e0) flushInterior(); else flushBoundary();
#pragma unroll
          for (int e = 0; e < 4; e++) ax[e] = ay[e] = 0.f;
          gx = gy = 0.f;
          runStart = jb + q;
          cur++;
          eend = off[cur + 1];
          if (MODE == 1) {
            int nbt = batch[cur];
            if (nbt != bcur) {
              flushPool();
#pragma unroll
              for (int e = 0; e < 4; e++) pax[e] = pay[e] = 0.f;
              pgx = pgy = 0.f;
              bcur = nbt;
            }
          }
        }
        float w = __int_as_float(__builtin_amdgcn_readlane(mv.y, b * 8 + q));
#pragma unroll
        for (int e = 0; e < 4; e++) {
          ax[e] = fmaf(w, (float)rv[q][2 * e], ax[e]);
          ay[e] = fmaf(w, (float)rv[q][2 * e + 1], ay[e]);
        }
        if (MODE == 0) {
          gx = fmaf(w, gf[q], gx);
        } else {
          gx = fmaf(w, (float)gh[q][0], gx);
          gy = fmaf(w, (float)gh[q][1], gy);
        }
      }
    }
  }
  if (runStart >= e0 && eend <= e1) flushInterior(); else flushBoundary();
  if (MODE == 1) flushPool();
}

// ---------------- fixups for chunk-spanning runs ----------------
__global__ void k_fix1(const int* __restrict__ bnode, const int* __restrict__ bslot,
                       const int* __restrict__ off, const float* __restrict__ aggc,
                       float* __restrict__ agg1, float* __restrict__ g1,
                       const float* __restrict__ gb1, int nchunk) {
  int g = blockIdx.x * 4 + (threadIdx.x >> 6);
  int lane = threadIdx.x & 63;
  if (g >= nchunk) return;
  int nd;
  if (!span_head(bnode, bslot, off, g, nd)) return;
  const float* sp = aggc + (size_t)g * 640;
#pragma unroll
  for (int e = 0; e < 4; e++) {
    float2 v = ((const float2*)sp)[e * 64 + lane];
    ((float2*)agg1)[(size_t)nd * 256 + e * 64 + lane] = v;
  }
  if (lane < 32) g1[(size_t)nd * 32 + lane] = fmaxf(sp[512 + lane] + gb1[lane], 0.f);
}

__global__ void k_fix2(const int* __restrict__ bnode, const int* __restrict__ bslot,
                       const int* __restrict__ off, const float* __restrict__ aggc,
                       const int* __restrict__ batch, float* __restrict__ feats,
                       const float* __restrict__ gb2, float* __restrict__ hgate,
                       int nchunk, CurvPack cp) {
  int g = blockIdx.x * 4 + (threadIdx.x >> 6);
  int lane = threadIdx.x & 63;
  if (g >= nchunk) return;
  int nd;
  if (!span_head(bnode, bslot, off, g, nd)) return;
  int b = batch[nd];
  const float* sp = aggc + (size_t)g * 640;
#pragma unroll
  for (int e = 0; e < 4; e++) {
    float2 v = ((const float2*)sp)[e * 64 + lane];
    float n2 = wsum64(fmaf(v.x, v.x, v.y * v.y));
    float nraw = sqrtf(n2);
    float nnv = fmaxf(nraw, 1e-15f);
    float tk = tan_k_d(nnv, cp.k[e], cp.sk[e]);
    float s = tk / nnv;
    float pn = fmaxf(fabsf(tk) * (nraw / nnv), 1e-15f);
    float ps = proj_scale_d(pn, cp.k[e], cp.mx[e]);
    s *= ps;
    float nh = fmaxf(pn * ps, 1e-15f);
    float sc = artan_k_d(nh, cp.k[e], cp.sk[e]) / nh * s;
    float* fp = &feats[(size_t)b * 512 + e * 128 + lane * 2];
    atomicAdd(fp, sc * v.x);
    atomicAdd(fp + 1, sc * v.y);
  }
  float2 gv = ((const float2*)(sp + 512))[lane];
  float2 bb = ((const float2*)gb2)[lane];
  float* hp = &hgate[(size_t)b * 128 + lane * 2];
  atomicAdd(hp, fmaxf(gv.x + bb.x, 0.f));
  atomicAdd(hp + 1, fmaxf(gv.y + bb.y, 0.f));
}

// ---------------- gate GEMM 1 ----------------
__global__ __launch_bounds__(256) void k_gate1(const float* __restrict__ x,
                                               const float* __restrict__ gw1,
                                               float* __restrict__ m1, int n) {
  __shared__ float xT[64][68];
  __shared__ float Wt[64][36];
  int tid = threadIdx.x;
  int n0 = blockIdx.x * 64;
  int c = tid & 7, r = tid >> 3;
  float acc[2][4];
#pragma unroll
  for (int i = 0; i < 2; i++)
#pragma unroll
    for (int jj = 0; jj < 4; jj++) acc[i][jj] = 0.f;

  for (int kc = 0; kc < 2; kc++) {
    if (kc) __syncthreads();
#pragma unroll
    for (int it = 0; it < 8; it++) {
      int u = tid + it * 256;
      int j = u >> 6, kd = u & 63;
      Wt[kd][j] = gw1[j * 128 + kc * 64 + kd];
    }
#pragma unroll
    for (int it = 0; it < 4; it++) {
      int u = tid + it * 256;
      int node = u >> 4, c4 = u & 15;
      float4 v = make_float4(0.f, 0.f, 0.f, 0.f);
      if (n0 + node < n) v = ((const float4*)x)[(size_t)(n0 + node) * 32 + kc * 16 + c4];
      xT[4 * c4 + 0][node] = v.x;
      xT[4 * c4 + 1][node] = v.y;
      xT[4 * c4 + 2][node] = v.z;
      xT[4 * c4 + 3][node] = v.w;
    }
    __syncthreads();
#pragma unroll 8
    for (int kd = 0; kd < 64; kd++) {
      float2 av = *(const float2*)&xT[kd][r * 2];
      float4 bv = *(const float4*)&Wt[kd][c * 4];
      float a[2] = {av.x, av.y};
      float bbv[4] = {bv.x, bv.y, bv.z, bv.w};
#pragma unroll
      for (int i = 0; i < 2; i++)
#pragma unroll
        for (int jj = 0; jj < 4; jj++) acc[i][jj] = fmaf(a[i], bbv[jj], acc[i][jj]);
    }
  }
#pragma unroll
  for (int i = 0; i < 2; i++) {
    int node = n0 + r * 2 + i;
    if (node >= n) continue;
    ((float4*)m1)[(size_t)node * 8 + c] = make_float4(acc[i][0], acc[i][1], acc[i][2], acc[i][3]);
  }
}

// ---------------- gate GEMM 2 (fp16 out, contiguous rows of 128 halfs) ----------------
__global__ __launch_bounds__(256) void k_gate2(const float* __restrict__ g1,
                                               const float* __restrict__ gw2,
                                               f16* __restrict__ m2, int n) {
  __shared__ float xT[32][68];
  __shared__ float Wt[32][132];
  int tid = threadIdx.x;
  int n0 = blockIdx.x * 64;
  int c = tid & 15, r = tid >> 4;
  float acc[4][8];
#pragma unroll
  for (int i = 0; i < 4; i++)
#pragma unroll
    for (int jj = 0; jj < 8; jj++) acc[i][jj] = 0.f;

#pragma unroll
  for (int it = 0; it < 16; it++) {
    int u = tid + it * 256;
    int j = u >> 5, kd = u & 31;
    Wt[kd][j] = gw2[j * 32 + kd];
  }
#pragma unroll
  for (int it = 0; it < 2; it++) {
    int u = tid + it * 256;
    int node = u >> 3, c4 = u & 7;
    float4 v = make_float4(0.f, 0.f, 0.f, 0.f);
    if (n0 + node < n) v = ((const float4*)g1)[(size_t)(n0 + node) * 8 + c4];
    xT[4 * c4 + 0][node] = v.x;
    xT[4 * c4 + 1][node] = v.y;
    xT[4 * c4 + 2][node] = v.z;
    xT[4 * c4 + 3][node] = v.w;
  }
  __syncthreads();
#pragma unroll 8
  for (int kd = 0; kd < 32; kd++) {
    float4 av = *(const float4*)&xT[kd][r * 4];
    float4 b0 = *(const float4*)&Wt[kd][c * 8];
    float4 b1 = *(const float4*)&Wt[kd][c * 8 + 4];
    float a[4] = {av.x, av.y, av.z, av.w};
    float bbv[8] = {b0.x, b0.y, b0.z, b0.w, b1.x, b1.y, b1.z, b1.w};
#pragma unroll
    for (int i = 0; i < 4; i++)
#pragma unroll
      for (int jj = 0; jj < 8; jj++) acc[i][jj] = fmaf(a[i], bbv[jj], acc[i][jj]);
  }
#pragma unroll
  for (int i = 0; i < 4; i++) {
    int node = n0 + r * 4 + i;
    if (node >= n) continue;
    f16x8 hv;
#pragma unroll
    for (int jj = 0; jj < 8; jj++) hv[jj] = (f16)acc[i][jj];
    *((f16x8*)(m2 + (size_t)node * 128) + c) = hv;
  }
}

// ---------------- final ----------------
__global__ __launch_bounds__(128) void k_final(const float* __restrict__ feats,
                                               const float* __restrict__ hgate,
                                               const float* __restrict__ counts,
                                               const float* __restrict__ gate_u,
                                               const float* __restrict__ tau_raw,
                                               float* __restrict__ out, CurvPack cp) {
  __shared__ float l2[2];
  int b = blockIdx.x;
  int j = threadIdx.x;
  float cnt = fmaxf(counts[b], 1.f);
  float hg = hgate[(size_t)b * 128 + j] / cnt;

  auto bsum = [&](float v) -> float {
    v = wsum64(v);
    __syncthreads();
    if ((j & 63) == 0) l2[j >> 6] = v;
    __syncthreads();
    return l2[0] + l2[1];
  };

  float nhg2 = bsum(hg * hg);
  float nhgraw = sqrtf(nhg2);
  float nhg = fmaxf(nhgraw, 1e-15f);

  float d[4], tau[4];
#pragma unroll
  for (int i = 0; i < 4; i++) {
    float kv = cp.k[i], sk = cp.sk[i], mxn = cp.mx[i];
    float tk = tan_k_d(nhg, kv, sk);
    float s = tk / nhg;
    float pn = fmaxf(fabsf(tk) * (nhgraw / nhg), 1e-15f);
    s *= proj_scale_d(pn, kv, mxn);
    float zk = s * hg;

    float u = gate_u[i * 128 + j];
    float nu2 = bsum(u * u);
    float nuraw = sqrtf(nu2);
    float nu = fmaxf(nuraw, 1e-15f);
    float tku = tan_k_d(nu, kv, sk);
    float su = tku / nu;
    float pnu = fmaxf(fabsf(tku) * (nuraw / nu), 1e-15f);
    su *= proj_scale_d(pnu, kv, mxn);
    float yk = su * u;

    float xv = -zk;
    float x2 = bsum(xv * xv);
    float y2 = bsum(yk * yk);
    float xy = bsum(xv * yk);
    float A = 1.f - 2.f * kv * xy - kv * y2;
    float C = 1.f + kv * x2;
    float den = fmaxf(1.f - 2.f * kv * xy + (kv * kv) * x2 * y2, 1e-15f);
    float ma = (A * xv + C * yk) / den;
    float m2 = bsum(ma * ma);
    float mraw = sqrtf(m2);
    float ps2 = proj_scale_d(fmaxf(mraw, 1e-15f), kv, mxn);
    float nm = fmaxf(ps2 * mraw, 1e-15f);
    d[i] = 2.f * artan_k_d(nm, kv, sk);

    float tr = tau_raw[i];
    tau[i] = fminf(fmaxf(log1pf(expf(tr)) + 0.05f, 0.05f), 10.f);
  }

  float xi[4];
  float mxv = -1e30f;
#pragma unroll
  for (int i = 0; i < 4; i++) {
    xi[i] = -d[i] / tau[i];
    mxv = fmaxf(mxv, xi[i]);
  }
  float es = 0.f, e[4];
#pragma unroll
  for (int i = 0; i < 4; i++) {
    e[i] = expf(xi[i] - mxv);
    es += e[i];
  }
  float w[4];
#pragma unroll
  for (int i = 0; i < 4; i++) w[i] = e[i] / es;

#pragma unroll
  for (int i = 0; i < 4; i++)
    out[(size_t)b * 512 + i * 128 + j] = feats[(size_t)b * 512 + i * 128 + j] / cnt * w[i];

  if (j < 4) {
    out[65536 + b * 4 + j] = w[j];
    out[66048 + b * 4 + j] = d[j];
  }
  if (b == 0 && j < 4) out[66560 + j] = tau[j];
}

// ---------------- host launcher ----------------
extern "C" void kernel_launch(void* const* d_in, const int* in_sizes, int n_in,
                              void* d_out, int out_size, void* d_ws, size_t ws_size,
                              hipStream_t stream) {
  const float* x = (const float*)d_in[0];
  const int* ei = (const int*)d_in[1];
  const int* batch = (const int*)d_in[2];
  const float* ew1 = (const float*)d_in[3];
  const float* eb1 = (const float*)d_in[4];
  const float* ew2 = (const float*)d_in[5];
  const float* eb2 = (const float*)d_in[6];
  const float* gw1 = (const float*)d_in[7];
  const float* gb1 = (const float*)d_in[8];
  const float* gw2 = (const float*)d_in[9];
  const float* gb2 = (const float*)d_in[10];
  const float* gu = (const float*)d_in[11];
  const float* traw = (const float*)d_in[12];
  float* out = (float*)d_out;

  const int N = NN, E = EE, ET = ETOT, B = BB;

  float* ws = (float*)d_ws;
  size_t o = 0;
  f16* t4 = (f16*)ws;       o += (size_t)N * 256;   // N*512 halfs, granule-interleaved
  float* agg1 = ws + o;     o += (size_t)N * 512;   // layer-1 raw agg, [node][ex*128+d]
  float* aggc = ws + o;     o += (size_t)NCHUNK * 640;  // boundary accum (512 exp + 128 gate)
  float* deg = ws + o;      o += N;                 // becomes dinv
  float* counts = ws + o;   o += 256;
  float* feats = ws + o;    o += (size_t)B * 512;
  float* hg = ws + o;       o += (size_t)B * 128;
  float* biasb = ws + o;    o += 8 * 132;
  f16* whi = (f16*)(ws + o);    o += 8 * 16384 / 2;
  f16* wlo = (f16*)(ws + o);    o += 8 * 16384 / 2;
  float* m1 = ws + o;       o += (size_t)N * 32;    // gate hidden pre-agg
  float* g1 = ws + o;       o += (size_t)N * 32;    // gate hidden post-relu
  f16* tg = (f16*)(ws + o); o += (size_t)N * 64;    // gate out f16, [node][128]
  int* ideg = (int*)(ws + o);   o += N;
  int* csroff = (int*)(ws + o); o += N + 8;
  int* cursor = (int*)(ws + o); o += N;
  int* boff = (int*)(ws + o);   o += 136;
  int* bsum = (int*)(ws + o);   o += 256;
  int* bnode = (int*)(ws + o);  o += NCHUNK + 8;
  int* bslot = (int*)(ws + o);  o += NCHUNK + 8;
  int2* esw = (int2*)(ws + o);  o += (size_t)2 * ET;

  hipMemsetAsync(counts, 0, (256 + (size_t)B * 512 + (size_t)B * 128) * sizeof(float), stream);

  const double curvs[4] = {-1.0, 0.0, 1.0, -0.5};
  CurvPack cp;
  for (int i = 0; i < 4; i++) {
    double kd = curvs[i];
    double skd = sqrt(fabs(kd));
    cp.k[i] = (float)kd;
    cp.sk[i] = (float)skd;
    cp.mx[i] = (kd < 0) ? (float)((1.0 - 1e-5) / skd) : 3.0e38f;
    // fast-path threshold: |agg| below this => logmap0(expmap0(v)) == v
    if (kd < 0) {
      double thr = 6.0 / skd;  // tanh(6.0)=0.9999877 < 1-1e-5 => no clamp
      cp.thr2[i] = (float)(thr * thr);
    } else if (kd > 0) {
      double thr = 1.5 / skd;  // < pi/2 => no tan wrap
      cp.thr2[i] = (float)(thr * thr);
    } else {
      cp.thr2[i] = 3.0e38f;    // k=0: identity always
    }
  }

  k_init<<<(N + 255) / 256, 256, 0, stream>>>(deg, N);
  k_counts<<<1, 256, 0, stream>>>(batch, boff, counts, N);
  k_deg<<<(E + 255) / 256, 256, 0, stream>>>(ei, deg, E);
  k_dinv<<<(N + 255) / 256, 256, 0, stream>>>(deg, ideg, N);
  k_scanA<<<SCB, 256, 0, stream>>>(ideg, bsum, N);
  k_scanB<<<1, 256, 0, stream>>>(bsum, SCB);
  k_scanC<<<SCB, 256, 0, stream>>>(ideg, bsum, csroff, cursor, N);
  k_bnodes<<<(NCHUNK + 255) / 256, 256, 0, stream>>>(csroff, bnode, NCHUNK, N);
  k_bslot<<<(NCHUNK + 255) / 256, 256, 0, stream>>>(bnode, bslot, NCHUNK);
  k_place<<<(ET + 255) / 256, 256, 0, stream>>>(ei, deg, cursor, esw, E, N);
  k_biaspt_all<<<8, 128, 0, stream>>>(eb1, eb2, biasb, cp);
  k_w2h<<<512, 256, 0, stream>>>(ew1, ew2, whi, wlo);
  k_gate1<<<(N + 63) / 64, 256, 0, stream>>>(x, gw1, m1, N);

  const int aggBlocks = (NCHUNK + 3) / 4;
  dim3 mfmaGrid((N + 15) / 16, 4);

  // ---- layer 1 (all 4 experts fused) + gate hidden ----
  k_matmfma<<<mfmaGrid, 256, 0, stream>>>(x, 128, 0, whi, wlo, biasb, 0, t4, N, cp);
  k_zeroc<<<aggBlocks, 256, 0, stream>>>(bnode, bslot, csroff, aggc, NCHUNK);
  k_aggF<0><<<aggBlocks, 256, 0, stream>>>(esw, csroff, bnode, bslot, batch,
                                           (const f16x8*)t4, m1, nullptr, agg1, aggc, g1,
                                           nullptr, gb1, nullptr, ET, cp);
  k_fix1<<<aggBlocks, 256, 0, stream>>>(bnode, bslot, csroff, aggc, agg1, g1, gb1, NCHUNK);
  k_gate2<<<(N + 63) / 64, 256, 0, stream>>>(g1, gw2, tg, N);

  // ---- layer 2 + gate out pooling ----
  k_matmfma<<<mfmaGrid, 256, 0, stream>>>(agg1, 512, 128, whi, wlo, biasb, 1, t4, N, cp);
  k_zeroc<<<aggBlocks, 256, 0, stream>>>(bnode, bslot, csroff, aggc, NCHUNK);
  k_aggF<1><<<aggBlocks, 256, 0, stream>>>(esw, csroff, bnode, bslot, batch,
                                           (const f16x8*)t4, nullptr, (const f16x2*)tg,
                                           nullptr, aggc, nullptr, feats, gb2, hg, ET, cp);
  k_fix2<<<aggBlocks, 256, 0, stream>>>(bnode, bslot, csroff, aggc, batch, feats, gb2, hg,
                                        NCHUNK, cp);

  k_final<<<B, 128, 0, stream>>>(feats, hg, counts, gu, traw, out, cp);

  (void)in_sizes; (void)n_in; (void)out_size; (void)ws_size;
}

// Round 4
// 963.280 us; speedup vs baseline: 1.1117x; 1.1095x over previous
//
#include <hip/hip_runtime.h>
#include <math.h>

// ---------------- constants ----------------
#define NN 50000
#define EE 800000
#define ETOT (EE + NN)
#define BB 128
#define DIM 128
#define GHID 32
#define CHUNK 128
#define NCHUNK ((ETOT + CHUNK - 1) / CHUNK)
#define SCB 196  // scan blocks: 196*256 >= 50000

typedef _Float16 f16;
typedef _Float16 f16x2 __attribute__((ext_vector_type(2)));
typedef _Float16 f16x8 __attribute__((ext_vector_type(8)));
typedef float f32x4 __attribute__((ext_vector_type(4)));

struct CurvPack {
  float k[4], sk[4], mx[4], thr2[4];
};

// ---------------- device math helpers ----------------
__device__ __forceinline__ float wsum64(float v) {
#pragma unroll
  for (int m = 32; m; m >>= 1) v += __shfl_xor(v, m, 64);
  return v;
}

__device__ __forceinline__ float tan_k_d(float x, float kv, float sk) {
  if (kv > 0.f) return tanf(x * sk) / sk;
  if (kv < 0.f) return tanhf(x * sk) / sk;
  return x;
}

__device__ __forceinline__ float artan_k_d(float x, float kv, float sk) {
  if (kv > 0.f) return atanf(x * sk) / sk;
  if (kv < 0.f) {
    float t = x * sk;
    t = fminf(fmaxf(t, -1.f + 1e-7f), 1.f - 1e-7f);
    return atanhf(t) / sk;
  }
  return x;
}

__device__ __forceinline__ float proj_scale_d(float n, float kv, float maxn) {
  if (kv < 0.f && n > maxn) return maxn / n;
  return 1.f;
}

// ---------------- graph preprocessing ----------------
__global__ void k_init(float* __restrict__ deg, int n) {
  int i = blockIdx.x * 256 + threadIdx.x;
  if (i < n) deg[i] = 1.0f;  // self loop
}

__global__ void k_counts(const int* __restrict__ batch, int* __restrict__ boff,
                         float* __restrict__ counts, int n) {
  int b = threadIdx.x;
  if (b <= 128) {
    int lo = 0, hi = n;
    while (lo < hi) {
      int mid = (lo + hi) >> 1;
      if (batch[mid] < b) lo = mid + 1; else hi = mid;
    }
    boff[b] = lo;
  }
  __syncthreads();
  if (b < 128) counts[b] = (float)(boff[b + 1] - boff[b]);
}

__global__ void k_deg(const int* __restrict__ ei, float* __restrict__ deg, int e) {
  int i = blockIdx.x * 256 + threadIdx.x;
  if (i < e) atomicAdd(&deg[ei[e + i]], 1.0f);
}

__global__ void k_dinv(float* __restrict__ deg, int* __restrict__ ideg, int n) {
  int i = blockIdx.x * 256 + threadIdx.x;
  if (i < n) {
    float d = deg[i];
    ideg[i] = (int)(d + 0.5f);
    deg[i] = 1.0f / sqrtf(d);
  }
}

// ---------------- parallel scan ----------------
__global__ void k_scanA(const int* __restrict__ ideg, int* __restrict__ bsum, int n) {
  __shared__ int ls[4];
  int i = blockIdx.x * 256 + threadIdx.x;
  int v = (i < n) ? ideg[i] : 0;
#pragma unroll
  for (int m = 1; m < 64; m <<= 1) v += __shfl_xor(v, m, 64);
  if ((threadIdx.x & 63) == 0) ls[threadIdx.x >> 6] = v;
  __syncthreads();
  if (threadIdx.x == 0) bsum[blockIdx.x] = ls[0] + ls[1] + ls[2] + ls[3];
}

__global__ void k_scanB(int* __restrict__ bsum, int nb) {
  __shared__ int wsh[4];
  int tid = threadIdx.x;
  int lane = tid & 63, w = tid >> 6;
  int v = (tid < nb) ? bsum[tid] : 0;
  int x = v;
#pragma unroll
  for (int o = 1; o < 64; o <<= 1) {
    int t = __shfl_up(x, o, 64);
    if (lane >= o) x += t;
  }
  if (lane == 63) wsh[w] = x;
  __syncthreads();
  int add = 0;
  for (int k2 = 0; k2 < w; k2++) add += wsh[k2];
  if (tid < nb) bsum[tid] = add + x - v;
}

__global__ void k_scanC(const int* __restrict__ ideg, const int* __restrict__ bsum,
                        int* __restrict__ off, int* __restrict__ cursor, int n) {
  __shared__ int wsh[4];
  int i = blockIdx.x * 256 + threadIdx.x;
  int lane = threadIdx.x & 63, w = threadIdx.x >> 6;
  int v = (i < n) ? ideg[i] : 0;
  int x = v;
#pragma unroll
  for (int o = 1; o < 64; o <<= 1) {
    int t = __shfl_up(x, o, 64);
    if (lane >= o) x += t;
  }
  if (lane == 63) wsh[w] = x;
  __syncthreads();
  int add = bsum[blockIdx.x];
  for (int k2 = 0; k2 < w; k2++) add += wsh[k2];
  int excl = add + x - v;
  if (i < n) {
    off[i] = excl;
    cursor[i] = excl;
  }
  if (i == n - 1) off[n] = excl + v;
}

// ---------------- chunk head nodes + first-occurrence slots ----------------
__global__ void k_bnodes(const int* __restrict__ off, int* __restrict__ bnode, int nchunk,
                         int n) {
  int g = blockIdx.x * 256 + threadIdx.x;
  if (g >= nchunk) return;
  int e0 = g * CHUNK;
  int lo = 0, hi = n;
  while (hi - lo > 1) {
    int mid = (lo + hi) >> 1;
    if (off[mid] <= e0) lo = mid; else hi = mid;
  }
  bnode[g] = lo;
}

__global__ void k_bslot(const int* __restrict__ bnode, int* __restrict__ bslot, int nchunk) {
  int g = blockIdx.x * 256 + threadIdx.x;
  if (g >= nchunk) return;
  int v = bnode[g];
  int lo = 0, hi = g;
  while (lo < hi) {
    int mid = (lo + hi) >> 1;
    if (bnode[mid] < v) lo = mid + 1; else hi = mid;
  }
  bslot[g] = lo;
}

__device__ __forceinline__ bool span_head(const int* bnode, const int* bslot, const int* off,
                                          int g, int& nd) {
  if (bslot[g] != g) return false;
  nd = bnode[g];
  int s = off[nd], e = off[nd + 1];
  return (s / CHUNK) != ((e - 1) / CHUNK);
}

// zero spanning boundary slots of aggc (640 floats per slot)
__global__ void k_zeroc(const int* __restrict__ bnode, const int* __restrict__ bslot,
                        const int* __restrict__ off, float* __restrict__ aggc, int nchunk) {
  int g = blockIdx.x * 4 + (threadIdx.x >> 6);
  int lane = threadIdx.x & 63;
  if (g >= nchunk) return;
  int nd;
  if (!span_head(bnode, bslot, off, g, nd)) return;
  float2 z = make_float2(0.f, 0.f);
#pragma unroll
  for (int i = 0; i < 5; i++) ((float2*)aggc)[(size_t)g * 320 + i * 64 + lane] = z;
}

// ---------------- edge placement ----------------
__global__ void k_place(const int* __restrict__ ei, const float* __restrict__ dinv,
                        int* __restrict__ cursor, int2* __restrict__ esw, int e, int n) {
  int i = blockIdx.x * 256 + threadIdx.x;
  int et = e + n;
  if (i >= et) return;
  int r_, c_;
  if (i < e) {
    r_ = ei[i];
    c_ = ei[e + i];
  } else {
    r_ = i - e;
    c_ = i - e;
  }
  int p = atomicAdd(&cursor[c_], 1);
  esw[p] = make_int2(r_, __float_as_int(dinv[r_] * dinv[c_]));
}

// ---------------- bias points ----------------
__global__ void k_biaspt_all(const float* __restrict__ eb1, const float* __restrict__ eb2,
                             float* __restrict__ biasb, CurvPack cp) {
  __shared__ float l2[2];
  int blk = blockIdx.x;  // ex*2 + layer
  int ex = blk >> 1, layer = blk & 1;
  float kv = cp.k[ex], sk = cp.sk[ex], maxn = cp.mx[ex];
  const float* b = (layer ? eb2 : eb1) + ex * 128;
  float* outb = biasb + blk * 132;
  int j = threadIdx.x;
  float v = b[j];
  float n2 = wsum64(v * v);
  if ((j & 63) == 0) l2[j >> 6] = n2;
  __syncthreads();
  n2 = l2[0] + l2[1];
  float nraw = sqrtf(n2);
  float nnv = fmaxf(nraw, 1e-15f);
  float tk = tan_k_d(nnv, kv, sk);
  float s = tk / nnv;
  float pn = fmaxf(fabsf(tk) * (nraw / nnv), 1e-15f);
  float ps = proj_scale_d(pn, kv, maxn);
  float bp = ps * s * v;
  outb[j] = bp;
  float y2v = wsum64(bp * bp);
  __syncthreads();
  if ((j & 63) == 0) l2[j >> 6] = y2v;
  __syncthreads();
  if (j == 0) outb[128] = l2[0] + l2[1];
}

// ---------------- W -> fp16 hi/lo split ----------------
__global__ void k_w2h(const float* __restrict__ ew1, const float* __restrict__ ew2,
                      f16* __restrict__ whi, f16* __restrict__ wlo) {
  int i = blockIdx.x * 256 + threadIdx.x;
  if (i >= 8 * 16384) return;
  int slot = i >> 14;
  int r = i & 16383;
  int ex = slot >> 1, layer = slot & 1;
  float w = (layer ? ew2 : ew1)[ex * 16384 + r];
  f16 h = (f16)w;
  whi[i] = h;
  wlo[i] = (f16)(w - (float)h);
}

// ---------------- MFMA expert GEMM (fp32 A split in-kernel; A-row norm fused) -------
// grid.y = expert. Output t interleaved: half offset (d>>1)*8 + ex*2 + (d&1).
__global__ __launch_bounds__(256) void k_matmfma(
    const float* __restrict__ A, int astr, int aoffPerEx,
    const f16* __restrict__ whiB, const f16* __restrict__ wloB,
    const float* __restrict__ biasB, int layer, f16* __restrict__ tout, int n,
    CurvPack cp) {
  __shared__ float red[3][16][4];
  __shared__ float redT[16][4];
  __shared__ float nAs[16], nCs[16], nL[16];
  int ex = blockIdx.y;
  float kv = cp.k[ex], sk = cp.sk[ex], maxn = cp.mx[ex];
  const f16* whi = whiB + (size_t)(ex * 2 + layer) * 16384;
  const f16* wlo = wloB + (size_t)(ex * 2 + layer) * 16384;
  const float* biasb = biasB + (ex * 2 + layer) * 132;

  int tid = threadIdx.x;
  int w = tid >> 6;
  int lane = tid & 63;
  int col = lane & 15;
  int quad = lane >> 4;
  int n0w = blockIdx.x * 16;
  if (n0w >= n) return;

  int anodec = min(n0w + col, n - 1);
  const float* arow = A + (size_t)anodec * astr + ex * aoffPerEx;
  int jt0 = w * 2;

  f32x4 acc[2];
  acc[0] = (f32x4){0.f, 0.f, 0.f, 0.f};
  acc[1] = (f32x4){0.f, 0.f, 0.f, 0.f};
  float a_n2 = 0.f;

#pragma unroll
  for (int kc = 0; kc < 4; kc++) {
    int kb = kc * 32 + quad * 8;
    float4 a0 = *(const float4*)(arow + kb);
    float4 a1 = *(const float4*)(arow + kb + 4);
    float av[8] = {a0.x, a0.y, a0.z, a0.w, a1.x, a1.y, a1.z, a1.w};
    f16x8 Ah, Al;
#pragma unroll
    for (int i = 0; i < 8; i++) {
      a_n2 = fmaf(av[i], av[i], a_n2);
      f16 h = (f16)av[i];
      Ah[i] = h;
      Al[i] = (f16)(av[i] - (float)h);
    }
#pragma unroll
    for (int j2 = 0; j2 < 2; j2++) {
      const f16* bh = whi + (size_t)((jt0 + j2) * 16 + col) * 128 + kb;
      const f16* bl = wlo + (size_t)((jt0 + j2) * 16 + col) * 128 + kb;
      f16x8 Bh = *(const f16x8*)bh;
      f16x8 Bl = *(const f16x8*)bl;
      acc[j2] = __builtin_amdgcn_mfma_f32_16x16x32_f16(Ah, Bh, acc[j2], 0, 0, 0);
      acc[j2] = __builtin_amdgcn_mfma_f32_16x16x32_f16(Ah, Bl, acc[j2], 0, 0, 0);
      acc[j2] = __builtin_amdgcn_mfma_f32_16x16x32_f16(Al, Bh, acc[j2], 0, 0, 0);
    }
  }
  // reduce per-quad partial norms across quads (per col)
  a_n2 += __shfl_xor(a_n2, 16, 64);
  a_n2 += __shfl_xor(a_n2, 32, 64);

  float bpj[2];
  bpj[0] = biasb[jt0 * 16 + col];
  bpj[1] = biasb[(jt0 + 1) * 16 + col];
  float y2 = biasb[128];

#pragma unroll
  for (int r = 0; r < 4; r++) {
    float s0 = 0.f, s1 = 0.f, s2 = 0.f;
#pragma unroll
    for (int j2 = 0; j2 < 2; j2++) {
      float v = acc[j2][r];
      s0 = fmaf(v, v, s0);
      s1 += fabsf(v);
      s2 = fmaf(v, bpj[j2], s2);
    }
#pragma unroll
    for (int m = 1; m < 16; m <<= 1) {
      s0 += __shfl_xor(s0, m, 64);
      s1 += __shfl_xor(s1, m, 64);
      s2 += __shfl_xor(s2, m, 64);
    }
    if (col == 0) {
      red[0][quad * 4 + r][w] = s0;
      red[1][quad * 4 + r][w] = s1;
      red[2][quad * 4 + r][w] = s2;
    }
  }
  __syncthreads();

  if (tid < 16) {
    // expmap0 scale from the A-row norm (was k_nodeprep / MODE0-flush)
    float nraw0 = sqrtf(a_n2);
    float nnv0 = fmaxf(nraw0, 1e-15f);
    float tk0 = tan_k_d(nnv0, kv, sk);
    float pn0 = fmaxf(fabsf(tk0) * (nraw0 / nnv0), 1e-15f);
    float ps0 = proj_scale_d(pn0, kv, maxn);
    float sc = (tk0 / nnv0) * ps0;
    float xnr = pn0 * ps0;

    float s0f = (red[0][tid][0] + red[0][tid][1] + red[0][tid][2] + red[0][tid][3]) * sc * sc;
    float s1f = (red[1][tid][0] + red[1][tid][1] + red[1][tid][2] + red[1][tid][3]) * fabsf(sc);
    float s2f = (red[2][tid][0] + red[2][tid][1] + red[2][tid][2] + red[2][tid][3]) * sc;
    float xn = fmaxf(xnr, 1e-15f);
    float mxraw = sqrtf(s0f);
    float mxv = fmaxf(mxraw, 1e-15f);
    float ar = artan_k_d(xn, kv, sk);
    float c1 = tan_k_d(mxv / xn * ar, kv, sk);
    float s = (s1f == 0.f) ? 0.f : c1 / mxv;
    float pn = fmaxf(fabsf(c1) * (mxraw / mxv), 1e-15f);
    float ps = (s1f == 0.f) ? 1.f : proj_scale_d(pn, kv, maxn);
    s *= ps;
    float x2 = (s * s) * s0f;
    float xy = s * s2f;
    float Aa = 1.f - 2.f * kv * xy - kv * y2;
    float Cc = 1.f + kv * x2;
    float den = fmaxf(1.f - 2.f * kv * xy + (kv * kv) * x2 * y2, 1e-15f);
    nAs[tid] = Aa * s / den * sc;
    nCs[tid] = Cc / den;
  }
  __syncthreads();

#pragma unroll
  for (int r = 0; r < 4; r++) {
    int idx = quad * 4 + r;
    float Asc = nAs[idx], Cs = nCs[idx];
    float t0 = 0.f;
#pragma unroll
    for (int j2 = 0; j2 < 2; j2++) {
      float v = fmaf(Asc, acc[j2][r], Cs * bpj[j2]);
      t0 = fmaf(v, v, t0);
    }
#pragma unroll
    for (int m = 1; m < 16; m <<= 1) t0 += __shfl_xor(t0, m, 64);
    if (col == 0) redT[idx][w] = t0;
  }
  __syncthreads();

  if (tid < 16) {
    float t0f = redT[tid][0] + redT[tid][1] + redT[tid][2] + redT[tid][3];
    float nraw = sqrtf(t0f);
    float ps2 = proj_scale_d(fmaxf(nraw, 1e-15f), kv, maxn);
    float nh = fmaxf(ps2 * nraw, 1e-15f);
    nL[tid] = artan_k_d(nh, kv, sk) / nh * ps2;
  }
  __syncthreads();

#pragma unroll
  for (int r = 0; r < 4; r++) {
    int idx = quad * 4 + r;
    int gnode = n0w + idx;
    if (gnode >= n) continue;
    float Asc = nAs[idx], Cs = nCs[idx], L = nL[idx];
    f16* trow = tout + (size_t)gnode * 512;
#pragma unroll
    for (int j2 = 0; j2 < 2; j2++) {
      float v = fmaf(Asc, acc[j2][r], Cs * bpj[j2]);
      int d = (jt0 + j2) * 16 + col;
      trow[(d >> 1) * 8 + ex * 2 + (d & 1)] = (f16)(L * v);
    }
  }
}

// ---------------- fused multi-expert + gate edge sweep ----------------
// MODE 0: layer-1 experts -> agg1 (raw fp32) ; gate hidden (32-dim, m1) -> g1 relu
// MODE 1: layer-2 experts -> logmap0(expmap0) pooling into feats ;
//         gate out (128-dim f16 tg) -> relu pooling into hgate
// t row: 64 granules of f16x8 = {e0d0,e0d1,e1d0,e1d1,e2d0,e2d1,e3d0,e3d1} per dim pair.
// CHUNK=128: whole-chunk metadata in TWO int2/lane loads; batch loop fully unrolled so
// every readlane index is a compile-time constant. off[]/batch[] windows preloaded into
// registers (readlane with wave-uniform index) -> no dependent loads at run boundaries.
template <int MODE>
__global__ __launch_bounds__(256) void k_aggF(
    const int2* __restrict__ esw, const int* __restrict__ off,
    const int* __restrict__ bnode, const int* __restrict__ bslot,
    const int* __restrict__ batch, const f16x8* __restrict__ t,
    const float* __restrict__ gm1, const f16x2* __restrict__ tg,
    float* __restrict__ agg1, float* __restrict__ aggc,
    float* __restrict__ g1, float* __restrict__ feats,
    const float* __restrict__ gbias, float* __restrict__ hgate,
    int etot, CurvPack cp) {
  int gw = blockIdx.x * 4 + (threadIdx.x >> 6);
  int lane = threadIdx.x & 63;
  int e0 = gw * CHUNK;
  if (e0 >= etot) return;
  int e1 = min(e0 + CHUNK, etot);
  int lane31 = lane & 31;
  int bnHead = bnode[gw];
  int slotA = bslot[gw];
  int slotB = ((gw + 1) * CHUNK < etot) ? bslot[gw + 1] : slotA;

  // whole-chunk edge metadata: lane l holds edges e0+l and e0+64+l
  int2 mv0 = esw[min(e0 + lane, etot - 1)];
  int2 mv1 = esw[min(e0 + 64 + lane, etot - 1)];
  // register windows for run offsets and batch ids (readlane, uniform index)
  int offv = off[min(bnHead + lane, NN)];
  int batchv = 0;
  if (MODE == 1) batchv = batch[min(bnHead + lane, NN - 1)];

  int cur = bnHead;
  int runStart = __builtin_amdgcn_readlane(offv, 0);
  int eend = __builtin_amdgcn_readlane(offv, 1);

  auto nextOff = [&](int c1) -> int {  // off[c1], c1 wave-uniform
    int rel = c1 - bnHead;
    if (rel < 64) return __builtin_amdgcn_readlane(offv, rel);
    return off[c1];
  };
  auto curBatch = [&](int c) -> int {  // batch[c], c wave-uniform
    int rel = c - bnHead;
    if (rel < 64) return __builtin_amdgcn_readlane(batchv, rel);
    return batch[c];
  };

  float ax[4], ay[4], pax[4], pay[4];
#pragma unroll
  for (int e = 0; e < 4; e++) ax[e] = ay[e] = pax[e] = pay[e] = 0.f;
  float gx = 0.f, gy = 0.f, pgx = 0.f, pgy = 0.f;
  int bcur = (MODE == 1) ? __builtin_amdgcn_readlane(batchv, 0) : 0;
  float bbx, bby = 0.f;
  if (MODE == 0) {
    bbx = gbias[lane31];
  } else {
    float2 bb = ((const float2*)gbias)[lane];
    bbx = bb.x;
    bby = bb.y;
  }

  auto flushInterior = [&]() {
#pragma unroll
    for (int e = 0; e < 4; e++) {
      if (MODE == 0) {
        ((float2*)agg1)[(size_t)cur * 256 + e * 64 + lane] = make_float2(ax[e], ay[e]);
      } else {
        float n2 = wsum64(fmaf(ax[e], ax[e], ay[e] * ay[e]));
        if (n2 <= cp.thr2[e]) {
          pax[e] += ax[e];
          pay[e] += ay[e];
        } else {
          float nraw = sqrtf(n2);
          float nnv = fmaxf(nraw, 1e-15f);
          float tk = tan_k_d(nnv, cp.k[e], cp.sk[e]);
          float s = tk / nnv;
          float pn = fmaxf(fabsf(tk) * (nraw / nnv), 1e-15f);
          float ps = proj_scale_d(pn, cp.k[e], cp.mx[e]);
          s *= ps;
          float nh = fmaxf(pn * ps, 1e-15f);
          float sc = artan_k_d(nh, cp.k[e], cp.sk[e]) / nh * s;
          pax[e] = fmaf(sc, ax[e], pax[e]);
          pay[e] = fmaf(sc, ay[e], pay[e]);
        }
      }
    }
    if (MODE == 0) {
      if (lane < 32) g1[(size_t)cur * 32 + lane] = fmaxf(gx + bbx, 0.f);
    } else {
      pgx += fmaxf(gx + bbx, 0.f);
      pgy += fmaxf(gy + bby, 0.f);
    }
  };
  auto flushBoundary = [&]() {
    int slot = (cur == bnHead) ? slotA : slotB;
    float* dp = aggc + (size_t)slot * 640;
#pragma unroll
    for (int e = 0; e < 4; e++) {
      atomicAdd(dp + e * 128 + lane * 2, ax[e]);
      atomicAdd(dp + e * 128 + lane * 2 + 1, ay[e]);
    }
    if (MODE == 0) {
      if (lane < 32) atomicAdd(dp + 512 + lane, gx);
    } else {
      atomicAdd(dp + 512 + lane * 2, gx);
      atomicAdd(dp + 512 + lane * 2 + 1, gy);
    }
  };
  auto flushPool = [&]() {
#pragma unroll
    for (int e = 0; e < 4; e++) {
      float* fp = &feats[(size_t)bcur * 512 + e * 128 + lane * 2];
      atomicAdd(fp, pax[e]);
      atomicAdd(fp + 1, pay[e]);
    }
    float* hp = &hgate[(size_t)bcur * 128 + lane * 2];
    atomicAdd(hp, pgx);
    atomicAdd(hp + 1, pgy);
  };

  f16x8 rv[8];
  float gf[8];
  f16x2 gh[8];

#pragma unroll
  for (int b = 0; b < CHUNK / 8; b++) {
    int jb = e0 + b * 8;
    if (jb < e1) {
      const int2 mvsel = (b < 8) ? mv0 : mv1;  // b compile-time -> resolved statically
      // issue all row loads for this batch (addresses from registers, no mem dep)
#pragma unroll
      for (int q = 0; q < 8; q++) {
        int s = __builtin_amdgcn_readlane(mvsel.x, (b & 7) * 8 + q);
        rv[q] = t[(size_t)s * 64 + lane];
        if (MODE == 0) gf[q] = gm1[(size_t)s * 32 + lane31];
        else gh[q] = tg[(size_t)s * 64 + lane];
      }
      // consume
#pragma unroll
      for (int q = 0; q < 8; q++) {
        if (jb + q == eend) {
          if (runStart >= e0) flushInterior(); else flushBoundary();
#pragma unroll
          for (int e = 0; e < 4; e++) ax[e] = ay[e] = 0.f;
          gx = gy = 0.f;
          runStart = jb + q;
          cur++;
          eend = nextOff(cur + 1);
          if (MODE == 1) {
            int nbt = curBatch(cur);
            if (nbt != bcur) {
              flushPool();
#pragma unroll
              for (int e = 0; e < 4; e++) pax[e] = pay[e] = 0.f;
              pgx = pgy = 0.f;
              bcur = nbt;
            }
          }
        }
        float w = __int_as_float(__builtin_amdgcn_readlane(mvsel.y, (b & 7) * 8 + q));
#pragma unroll
        for (int e = 0; e < 4; e++) {
          ax[e] = fmaf(w, (float)rv[q][2 * e], ax[e]);
          ay[e] = fmaf(w, (float)rv[q][2 * e + 1], ay[e]);
        }
        if (MODE == 0) {
          gx = fmaf(w, gf[q], gx);
        } else {
          gx = fmaf(w, (float)gh[q][0], gx);
          gy = fmaf(w, (float)gh[q][1], gy);
        }
      }
    }
  }
  if (runStart >= e0 && eend <= e1) flushInterior(); else flushBoundary();
  if (MODE == 1) flushPool();
}

// ---------------- fixups for chunk-spanning runs ----------------
__global__ void k_fix1(const int* __restrict__ bnode, const int* __restrict__ bslot,
                       const int* __restrict__ off, const float* __restrict__ aggc,
                       float* __restrict__ agg1, float* __restrict__ g1,
                       const float* __restrict__ gb1, int nchunk) {
  int g = blockIdx.x * 4 + (threadIdx.x >> 6);
  int lane = threadIdx.x & 63;
  if (g >= nchunk) return;
  int nd;
  if (!span_head(bnode, bslot, off, g, nd)) return;
  const float* sp = aggc + (size_t)g * 640;
#pragma unroll
  for (int e = 0; e < 4; e++) {
    float2 v = ((const float2*)sp)[e * 64 + lane];
    ((float2*)agg1)[(size_t)nd * 256 + e * 64 + lane] = v;
  }
  if (lane < 32) g1[(size_t)nd * 32 + lane] = fmaxf(sp[512 + lane] + gb1[lane], 0.f);
}

__global__ void k_fix2(const int* __restrict__ bnode, const int* __restrict__ bslot,
                       const int* __restrict__ off, const float* __restrict__ aggc,
                       const int* __restrict__ batch, float* __restrict__ feats,
                       const float* __restrict__ gb2, float* __restrict__ hgate,
                       int nchunk, CurvPack cp) {
  int g = blockIdx.x * 4 + (threadIdx.x >> 6);
  int lane = threadIdx.x & 63;
  if (g >= nchunk) return;
  int nd;
  if (!span_head(bnode, bslot, off, g, nd)) return;
  int b = batch[nd];
  const float* sp = aggc + (size_t)g * 640;
#pragma unroll
  for (int e = 0; e < 4; e++) {
    float2 v = ((const float2*)sp)[e * 64 + lane];
    float n2 = wsum64(fmaf(v.x, v.x, v.y * v.y));
    float nraw = sqrtf(n2);
    float nnv = fmaxf(nraw, 1e-15f);
    float tk = tan_k_d(nnv, cp.k[e], cp.sk[e]);
    float s = tk / nnv;
    float pn = fmaxf(fabsf(tk) * (nraw / nnv), 1e-15f);
    float ps = proj_scale_d(pn, cp.k[e], cp.mx[e]);
    s *= ps;
    float nh = fmaxf(pn * ps, 1e-15f);
    float sc = artan_k_d(nh, cp.k[e], cp.sk[e]) / nh * s;
    float* fp = &feats[(size_t)b * 512 + e * 128 + lane * 2];
    atomicAdd(fp, sc * v.x);
    atomicAdd(fp + 1, sc * v.y);
  }
  float2 gv = ((const float2*)(sp + 512))[lane];
  float2 bb = ((const float2*)gb2)[lane];
  float* hp = &hgate[(size_t)b * 128 + lane * 2];
  atomicAdd(hp, fmaxf(gv.x + bb.x, 0.f));
  atomicAdd(hp + 1, fmaxf(gv.y + bb.y, 0.f));
}

// ---------------- gate GEMM 1 ----------------
__global__ __launch_bounds__(256) void k_gate1(const float* __restrict__ x,
                                               const float* __restrict__ gw1,
                                               float* __restrict__ m1, int n) {
  __shared__ float xT[64][68];
  __shared__ float Wt[64][36];
  int tid = threadIdx.x;
  int n0 = blockIdx.x * 64;
  int c = tid & 7, r = tid >> 3;
  float acc[2][4];
#pragma unroll
  for (int i = 0; i < 2; i++)
#pragma unroll
    for (int jj = 0; jj < 4; jj++) acc[i][jj] = 0.f;

  for (int kc = 0; kc < 2; kc++) {
    if (kc) __syncthreads();
#pragma unroll
    for (int it = 0; it < 8; it++) {
      int u = tid + it * 256;
      int j = u >> 6, kd = u & 63;
      Wt[kd][j] = gw1[j * 128 + kc * 64 + kd];
    }
#pragma unroll
    for (int it = 0; it < 4; it++) {
      int u = tid + it * 256;
      int node = u >> 4, c4 = u & 15;
      float4 v = make_float4(0.f, 0.f, 0.f, 0.f);
      if (n0 + node < n) v = ((const float4*)x)[(size_t)(n0 + node) * 32 + kc * 16 + c4];
      xT[4 * c4 + 0][node] = v.x;
      xT[4 * c4 + 1][node] = v.y;
      xT[4 * c4 + 2][node] = v.z;
      xT[4 * c4 + 3][node] = v.w;
    }
    __syncthreads();
#pragma unroll 8
    for (int kd = 0; kd < 64; kd++) {
      float2 av = *(const float2*)&xT[kd][r * 2];
      float4 bv = *(const float4*)&Wt[kd][c * 4];
      float a[2] = {av.x, av.y};
      float bbv[4] = {bv.x, bv.y, bv.z, bv.w};
#pragma unroll
      for (int i = 0; i < 2; i++)
#pragma unroll
        for (int jj = 0; jj < 4; jj++) acc[i][jj] = fmaf(a[i], bbv[jj], acc[i][jj]);
    }
  }
#pragma unroll
  for (int i = 0; i < 2; i++) {
    int node = n0 + r * 2 + i;
    if (node >= n) continue;
    ((float4*)m1)[(size_t)node * 8 + c] = make_float4(acc[i][0], acc[i][1], acc[i][2], acc[i][3]);
  }
}

// ---------------- gate GEMM 2 (fp16 out, contiguous rows of 128 halfs) ----------------
__global__ __launch_bounds__(256) void k_gate2(const float* __restrict__ g1,
                                               const float* __restrict__ gw2,
                                               f16* __restrict__ m2, int n) {
  __shared__ float xT[32][68];
  __shared__ float Wt[32][132];
  int tid = threadIdx.x;
  int n0 = blockIdx.x * 64;
  int c = tid & 15, r = tid >> 4;
  float acc[4][8];
#pragma unroll
  for (int i = 0; i < 4; i++)
#pragma unroll
    for (int jj = 0; jj < 8; jj++) acc[i][jj] = 0.f;

#pragma unroll
  for (int it = 0; it < 16; it++) {
    int u = tid + it * 256;
    int j = u >> 5, kd = u & 31;
    Wt[kd][j] = gw2[j * 32 + kd];
  }
#pragma unroll
  for (int it = 0; it < 2; it++) {
    int u = tid + it * 256;
    int node = u >> 3, c4 = u & 7;
    float4 v = make_float4(0.f, 0.f, 0.f, 0.f);
    if (n0 + node < n) v = ((const float4*)g1)[(size_t)(n0 + node) * 8 + c4];
    xT[4 * c4 + 0][node] = v.x;
    xT[4 * c4 + 1][node] = v.y;
    xT[4 * c4 + 2][node] = v.z;
    xT[4 * c4 + 3][node] = v.w;
  }
  __syncthreads();
#pragma unroll 8
  for (int kd = 0; kd < 32; kd++) {
    float4 av = *(const float4*)&xT[kd][r * 4];
    float4 b0 = *(const float4*)&Wt[kd][c * 8];
    float4 b1 = *(const float4*)&Wt[kd][c * 8 + 4];
    float a[4] = {av.x, av.y, av.z, av.w};
    float bbv[8] = {b0.x, b0.y, b0.z, b0.w, b1.x, b1.y, b1.z, b1.w};
#pragma unroll
    for (int i = 0; i < 4; i++)
#pragma unroll
      for (int jj = 0; jj < 8; jj++) acc[i][jj] = fmaf(a[i], bbv[jj], acc[i][jj]);
  }
#pragma unroll
  for (int i = 0; i < 4; i++) {
    int node = n0 + r * 4 + i;
    if (node >= n) continue;
    f16x8 hv;
#pragma unroll
    for (int jj = 0; jj < 8; jj++) hv[jj] = (f16)acc[i][jj];
    *((f16x8*)(m2 + (size_t)node * 128) + c) = hv;
  }
}

// ---------------- final ----------------
__global__ __launch_bounds__(128) void k_final(const float* __restrict__ feats,
                                               const float* __restrict__ hgate,
                                               const float* __restrict__ counts,
                                               const float* __restrict__ gate_u,
                                               const float* __restrict__ tau_raw,
                                               float* __restrict__ out, CurvPack cp) {
  __shared__ float l2[2];
  int b = blockIdx.x;
  int j = threadIdx.x;
  float cnt = fmaxf(counts[b], 1.f);
  float hg = hgate[(size_t)b * 128 + j] / cnt;

  auto bsum = [&](float v) -> float {
    v = wsum64(v);
    __syncthreads();
    if ((j & 63) == 0) l2[j >> 6] = v;
    __syncthreads();
    return l2[0] + l2[1];
  };

  float nhg2 = bsum(hg * hg);
  float nhgraw = sqrtf(nhg2);
  float nhg = fmaxf(nhgraw, 1e-15f);

  float d[4], tau[4];
#pragma unroll
  for (int i = 0; i < 4; i++) {
    float kv = cp.k[i], sk = cp.sk[i], mxn = cp.mx[i];
    float tk = tan_k_d(nhg, kv, sk);
    float s = tk / nhg;
    float pn = fmaxf(fabsf(tk) * (nhgraw / nhg), 1e-15f);
    s *= proj_scale_d(pn, kv, mxn);
    float zk = s * hg;

    float u = gate_u[i * 128 + j];
    float nu2 = bsum(u * u);
    float nuraw = sqrtf(nu2);
    float nu = fmaxf(nuraw, 1e-15f);
    float tku = tan_k_d(nu, kv, sk);
    float su = tku / nu;
    float pnu = fmaxf(fabsf(tku) * (nuraw / nu), 1e-15f);
    su *= proj_scale_d(pnu, kv, mxn);
    float yk = su * u;

    float xv = -zk;
    float x2 = bsum(xv * xv);
    float y2 = bsum(yk * yk);
    float xy = bsum(xv * yk);
    float A = 1.f - 2.f * kv * xy - kv * y2;
    float C = 1.f + kv * x2;
    float den = fmaxf(1.f - 2.f * kv * xy + (kv * kv) * x2 * y2, 1e-15f);
    float ma = (A * xv + C * yk) / den;
    float m2 = bsum(ma * ma);
    float mraw = sqrtf(m2);
    float ps2 = proj_scale_d(fmaxf(mraw, 1e-15f), kv, mxn);
    float nm = fmaxf(ps2 * mraw, 1e-15f);
    d[i] = 2.f * artan_k_d(nm, kv, sk);

    float tr = tau_raw[i];
    tau[i] = fminf(fmaxf(log1pf(expf(tr)) + 0.05f, 0.05f), 10.f);
  }

  float xi[4];
  float mxv = -1e30f;
#pragma unroll
  for (int i = 0; i < 4; i++) {
    xi[i] = -d[i] / tau[i];
    mxv = fmaxf(mxv, xi[i]);
  }
  float es = 0.f, e[4];
#pragma unroll
  for (int i = 0; i < 4; i++) {
    e[i] = expf(xi[i] - mxv);
    es += e[i];
  }
  float w[4];
#pragma unroll
  for (int i = 0; i < 4; i++) w[i] = e[i] / es;

#pragma unroll
  for (int i = 0; i < 4; i++)
    out[(size_t)b * 512 + i * 128 + j] = feats[(size_t)b * 512 + i * 128 + j] / cnt * w[i];

  if (j < 4) {
    out[65536 + b * 4 + j] = w[j];
    out[66048 + b * 4 + j] = d[j];
  }
  if (b == 0 && j < 4) out[66560 + j] = tau[j];
}

// ---------------- host launcher ----------------
extern "C" void kernel_launch(void* const* d_in, const int* in_sizes, int n_in,
                              void* d_out, int out_size, void* d_ws, size_t ws_size,
                              hipStream_t stream) {
  const float* x = (const float*)d_in[0];
  const int* ei = (const int*)d_in[1];
  const int* batch = (const int*)d_in[2];
  const float* ew1 = (const float*)d_in[3];
  const float* eb1 = (const float*)d_in[4];
  const float* ew2 = (const float*)d_in[5];
  const float* eb2 = (const float*)d_in[6];
  const float* gw1 = (const float*)d_in[7];
  const float* gb1 = (const float*)d_in[8];
  const float* gw2 = (const float*)d_in[9];
  const float* gb2 = (const float*)d_in[10];
  const float* gu = (const float*)d_in[11];
  const float* traw = (const float*)d_in[12];
  float* out = (float*)d_out;

  const int N = NN, E = EE, ET = ETOT, B = BB;

  float* ws = (float*)d_ws;
  size_t o = 0;
  f16* t4 = (f16*)ws;       o += (size_t)N * 256;   // N*512 halfs, granule-interleaved
  float* agg1 = ws + o;     o += (size_t)N * 512;   // layer-1 raw agg, [node][ex*128+d]
  float* aggc = ws + o;     o += (size_t)NCHUNK * 640;  // boundary accum (512 exp + 128 gate)
  float* deg = ws + o;      o += N;                 // becomes dinv
  float* counts = ws + o;   o += 256;
  float* feats = ws + o;    o += (size_t)B * 512;
  float* hg = ws + o;       o += (size_t)B * 128;
  float* biasb = ws + o;    o += 8 * 132;
  f16* whi = (f16*)(ws + o);    o += 8 * 16384 / 2;
  f16* wlo = (f16*)(ws + o);    o += 8 * 16384 / 2;
  float* m1 = ws + o;       o += (size_t)N * 32;    // gate hidden pre-agg
  float* g1 = ws + o;       o += (size_t)N * 32;    // gate hidden post-relu
  f16* tg = (f16*)(ws + o); o += (size_t)N * 64;    // gate out f16, [node][128]
  int* ideg = (int*)(ws + o);   o += N;
  int* csroff = (int*)(ws + o); o += N + 8;
  int* cursor = (int*)(ws + o); o += N;
  int* boff = (int*)(ws + o);   o += 136;
  int* bsum = (int*)(ws + o);   o += 256;
  int* bnode = (int*)(ws + o);  o += NCHUNK + 8;
  int* bslot = (int*)(ws + o);  o += NCHUNK + 8;
  int2* esw = (int2*)(ws + o);  o += (size_t)2 * ET;

  hipMemsetAsync(counts, 0, (256 + (size_t)B * 512 + (size_t)B * 128) * sizeof(float), stream);

  const double curvs[4] = {-1.0, 0.0, 1.0, -0.5};
  CurvPack cp;
  for (int i = 0; i < 4; i++) {
    double kd = curvs[i];
    double skd = sqrt(fabs(kd));
    cp.k[i] = (float)kd;
    cp.sk[i] = (float)skd;
    cp.mx[i] = (kd < 0) ? (float)((1.0 - 1e-5) / skd) : 3.0e38f;
    // fast-path threshold: |agg| below this => logmap0(expmap0(v)) == v
    if (kd < 0) {
      double thr = 6.0 / skd;  // tanh(6.0)=0.9999877 < 1-1e-5 => no clamp
      cp.thr2[i] = (float)(thr * thr);
    } else if (kd > 0) {
      double thr = 1.5 / skd;  // < pi/2 => no tan wrap
      cp.thr2[i] = (float)(thr * thr);
    } else {
      cp.thr2[i] = 3.0e38f;    // k=0: identity always
    }
  }

  k_init<<<(N + 255) / 256, 256, 0, stream>>>(deg, N);
  k_counts<<<1, 256, 0, stream>>>(batch, boff, counts, N);
  k_deg<<<(E + 255) / 256, 256, 0, stream>>>(ei, deg, E);
  k_dinv<<<(N + 255) / 256, 256, 0, stream>>>(deg, ideg, N);
  k_scanA<<<SCB, 256, 0, stream>>>(ideg, bsum, N);
  k_scanB<<<1, 256, 0, stream>>>(bsum, SCB);
  k_scanC<<<SCB, 256, 0, stream>>>(ideg, bsum, csroff, cursor, N);
  k_bnodes<<<(NCHUNK + 255) / 256, 256, 0, stream>>>(csroff, bnode, NCHUNK, N);
  k_bslot<<<(NCHUNK + 255) / 256, 256, 0, stream>>>(bnode, bslot, NCHUNK);
  k_place<<<(ET + 255) / 256, 256, 0, stream>>>(ei, deg, cursor, esw, E, N);
  k_biaspt_all<<<8, 128, 0, stream>>>(eb1, eb2, biasb, cp);
  k_w2h<<<512, 256, 0, stream>>>(ew1, ew2, whi, wlo);
  k_gate1<<<(N + 63) / 64, 256, 0, stream>>>(x, gw1, m1, N);

  const int aggBlocks = (NCHUNK + 3) / 4;
  dim3 mfmaGrid((N + 15) / 16, 4);

  // ---- layer 1 (all 4 experts fused) + gate hidden ----
  k_matmfma<<<mfmaGrid, 256, 0, stream>>>(x, 128, 0, whi, wlo, biasb, 0, t4, N, cp);
  k_zeroc<<<aggBlocks, 256, 0, stream>>>(bnode, bslot, csroff, aggc, NCHUNK);
  k_aggF<0><<<aggBlocks, 256, 0, stream>>>(esw, csroff, bnode, bslot, batch,
                                           (const f16x8*)t4, m1, nullptr, agg1, aggc, g1,
                                           nullptr, gb1, nullptr, ET, cp);
  k_fix1<<<aggBlocks, 256, 0, stream>>>(bnode, bslot, csroff, aggc, agg1, g1, gb1, NCHUNK);
  k_gate2<<<(N + 63) / 64, 256, 0, stream>>>(g1, gw2, tg, N);

  // ---- layer 2 + gate out pooling ----
  k_matmfma<<<mfmaGrid, 256, 0, stream>>>(agg1, 512, 128, whi, wlo, biasb, 1, t4, N, cp);
  k_zeroc<<<aggBlocks, 256, 0, stream>>>(bnode, bslot, csroff, aggc, NCHUNK);
  k_aggF<1><<<aggBlocks, 256, 0, stream>>>(esw, csroff, bnode, bslot, batch,
                                           (const f16x8*)t4, nullptr, (const f16x2*)tg,
                                           nullptr, aggc, nullptr, feats, gb2, hg, ET, cp);
  k_fix2<<<aggBlocks, 256, 0, stream>>>(bnode, bslot, csroff, aggc, batch, feats, gb2, hg,
                                        NCHUNK, cp);

  k_final<<<B, 128, 0, stream>>>(feats, hg, counts, gu, traw, out, cp);

  (void)in_sizes; (void)n_in; (void)out_size; (void)ws_size;
}

// Round 5
// 911.615 us; speedup vs baseline: 1.1747x; 1.0567x over previous
//
#include <hip/hip_runtime.h>
#include <math.h>

// ---------------- constants ----------------
#define NN 50000
#define EE 800000
#define ETOT (EE + NN)
#define BB 128
#define DIM 128
#define GHID 32
#define CHUNK 128
#define NCHUNK ((ETOT + CHUNK - 1) / CHUNK)
#define SCB 196  // scan blocks: 196*256 >= 50000

// mega0 block ranges
#define DEGB 3125            // (EE+255)/256
#define G1B 782              // (NN+63)/64
#define W2HB 512
#define MEGA0B (DEGB + G1B + W2HB + 1 + 8)
// megapre
#define PLACEB 3321          // (ETOT+255)/256
#define BNB ((NCHUNK + 255) / 256)

typedef _Float16 f16;
typedef _Float16 f16x2 __attribute__((ext_vector_type(2)));
typedef _Float16 f16x8 __attribute__((ext_vector_type(8)));
typedef float f32x4 __attribute__((ext_vector_type(4)));

struct CurvPack {
  float k[4], sk[4], mx[4], thr2[4];
};

// ---------------- device math helpers ----------------
__device__ __forceinline__ float wsum64(float v) {
#pragma unroll
  for (int m = 32; m; m >>= 1) v += __shfl_xor(v, m, 64);
  return v;
}

__device__ __forceinline__ float tan_k_d(float x, float kv, float sk) {
  if (kv > 0.f) return tanf(x * sk) / sk;
  if (kv < 0.f) return tanhf(x * sk) / sk;
  return x;
}

__device__ __forceinline__ float artan_k_d(float x, float kv, float sk) {
  if (kv > 0.f) return atanf(x * sk) / sk;
  if (kv < 0.f) {
    float t = x * sk;
    t = fminf(fmaxf(t, -1.f + 1e-7f), 1.f - 1e-7f);
    return atanhf(t) / sk;
  }
  return x;
}

__device__ __forceinline__ float proj_scale_d(float n, float kv, float maxn) {
  if (kv < 0.f && n > maxn) return maxn / n;
  return 1.f;
}

// ---------------- mega0: {deg atomics | gate1 | w2h | counts | biaspt} ----------------
__global__ __launch_bounds__(256) void k_mega0(
    const int* __restrict__ ei, float* __restrict__ deg, const int* __restrict__ batch,
    int* __restrict__ boff, float* __restrict__ counts, const float* __restrict__ eb1,
    const float* __restrict__ eb2, float* __restrict__ biasb, const float* __restrict__ ew1,
    const float* __restrict__ ew2, f16* __restrict__ whi, f16* __restrict__ wlo,
    const float* __restrict__ x, const float* __restrict__ gw1, float* __restrict__ m1,
    CurvPack cp) {
  __shared__ float smem[64 * 68 + 64 * 36];
  int bx = blockIdx.x;
  int tid = threadIdx.x;

  if (bx < DEGB) {  // degree atomics (deg pre-zeroed; self loop added in dinv)
    int i = bx * 256 + tid;
    if (i < EE) atomicAdd(&deg[ei[EE + i]], 1.0f);
    return;
  }
  bx -= DEGB;

  if (bx < G1B) {  // gate GEMM 1: m1 = x @ gw1^T
    float(*xT)[68] = (float(*)[68])smem;
    float(*Wt)[36] = (float(*)[36])(smem + 64 * 68);
    int n0 = bx * 64;
    int c = tid & 7, r = tid >> 3;
    float acc[2][4];
#pragma unroll
    for (int i = 0; i < 2; i++)
#pragma unroll
      for (int jj = 0; jj < 4; jj++) acc[i][jj] = 0.f;
    for (int kc = 0; kc < 2; kc++) {
      if (kc) __syncthreads();
#pragma unroll
      for (int it = 0; it < 8; it++) {
        int u = tid + it * 256;
        int j = u >> 6, kd = u & 63;
        Wt[kd][j] = gw1[j * 128 + kc * 64 + kd];
      }
#pragma unroll
      for (int it = 0; it < 4; it++) {
        int u = tid + it * 256;
        int node = u >> 4, c4 = u & 15;
        float4 v = make_float4(0.f, 0.f, 0.f, 0.f);
        if (n0 + node < NN) v = ((const float4*)x)[(size_t)(n0 + node) * 32 + kc * 16 + c4];
        xT[4 * c4 + 0][node] = v.x;
        xT[4 * c4 + 1][node] = v.y;
        xT[4 * c4 + 2][node] = v.z;
        xT[4 * c4 + 3][node] = v.w;
      }
      __syncthreads();
#pragma unroll 8
      for (int kd = 0; kd < 64; kd++) {
        float2 av = *(const float2*)&xT[kd][r * 2];
        float4 bv = *(const float4*)&Wt[kd][c * 4];
        float a[2] = {av.x, av.y};
        float bbv[4] = {bv.x, bv.y, bv.z, bv.w};
#pragma unroll
        for (int i = 0; i < 2; i++)
#pragma unroll
          for (int jj = 0; jj < 4; jj++) acc[i][jj] = fmaf(a[i], bbv[jj], acc[i][jj]);
      }
    }
#pragma unroll
    for (int i = 0; i < 2; i++) {
      int node = n0 + r * 2 + i;
      if (node >= NN) continue;
      ((float4*)m1)[(size_t)node * 8 + c] =
          make_float4(acc[i][0], acc[i][1], acc[i][2], acc[i][3]);
    }
    return;
  }
  bx -= G1B;

  if (bx < W2HB) {  // W -> fp16 hi/lo split
    int i = bx * 256 + tid;
    if (i >= 8 * 16384) return;
    int slot = i >> 14;
    int r = i & 16383;
    int ex = slot >> 1, layer = slot & 1;
    float w = (layer ? ew2 : ew1)[ex * 16384 + r];
    f16 h = (f16)w;
    whi[i] = h;
    wlo[i] = (f16)(w - (float)h);
    return;
  }
  bx -= W2HB;

  if (bx == 0) {  // batch counts
    int b = tid;
    if (b <= 128) {
      int lo = 0, hi = NN;
      while (lo < hi) {
        int mid = (lo + hi) >> 1;
        if (batch[mid] < b) lo = mid + 1; else hi = mid;
      }
      boff[b] = lo;
    }
    __syncthreads();
    if (b < 128) counts[b] = (float)(boff[b + 1] - boff[b]);
    return;
  }
  bx -= 1;

  {  // bias points, blk = bx in [0,8)
    float* l2 = smem;
    int ex = bx >> 1, layer = bx & 1;
    float kv = cp.k[ex], sk = cp.sk[ex], maxn = cp.mx[ex];
    const float* b = (layer ? eb2 : eb1) + ex * 128;
    float* outb = biasb + bx * 132;
    int j = tid;
    float v = (j < 128) ? b[j] : 0.f;
    float n2 = wsum64(v * v);
    if ((j & 63) == 0) l2[j >> 6] = n2;
    __syncthreads();
    n2 = l2[0] + l2[1];
    float nraw = sqrtf(n2);
    float nnv = fmaxf(nraw, 1e-15f);
    float tk = tan_k_d(nnv, kv, sk);
    float s = tk / nnv;
    float pn = fmaxf(fabsf(tk) * (nraw / nnv), 1e-15f);
    float ps = proj_scale_d(pn, kv, maxn);
    float bp = ps * s * v;
    if (j < 128) outb[j] = bp;
    float y2v = wsum64(bp * bp);
    __syncthreads();
    if ((j & 63) == 0) l2[j >> 6] = y2v;
    __syncthreads();
    if (j == 0) outb[128] = l2[0] + l2[1];
  }
}

// ---------------- dinv (adds self loop) ----------------
__global__ void k_dinv(float* __restrict__ deg, int* __restrict__ ideg, int n) {
  int i = blockIdx.x * 256 + threadIdx.x;
  if (i < n) {
    float d = deg[i] + 1.0f;  // self loop
    ideg[i] = (int)(d + 0.5f);
    deg[i] = 1.0f / sqrtf(d);
  }
}

// ---------------- parallel scan ----------------
__global__ void k_scanA(const int* __restrict__ ideg, int* __restrict__ bsum, int n) {
  __shared__ int ls[4];
  int i = blockIdx.x * 256 + threadIdx.x;
  int v = (i < n) ? ideg[i] : 0;
#pragma unroll
  for (int m = 1; m < 64; m <<= 1) v += __shfl_xor(v, m, 64);
  if ((threadIdx.x & 63) == 0) ls[threadIdx.x >> 6] = v;
  __syncthreads();
  if (threadIdx.x == 0) bsum[blockIdx.x] = ls[0] + ls[1] + ls[2] + ls[3];
}

__global__ void k_scanB(int* __restrict__ bsum, int nb) {
  __shared__ int wsh[4];
  int tid = threadIdx.x;
  int lane = tid & 63, w = tid >> 6;
  int v = (tid < nb) ? bsum[tid] : 0;
  int x = v;
#pragma unroll
  for (int o = 1; o < 64; o <<= 1) {
    int t = __shfl_up(x, o, 64);
    if (lane >= o) x += t;
  }
  if (lane == 63) wsh[w] = x;
  __syncthreads();
  int add = 0;
  for (int k2 = 0; k2 < w; k2++) add += wsh[k2];
  if (tid < nb) bsum[tid] = add + x - v;
}

__global__ void k_scanC(const int* __restrict__ ideg, const int* __restrict__ bsum,
                        int* __restrict__ off, int* __restrict__ cursor, int n) {
  __shared__ int wsh[4];
  int i = blockIdx.x * 256 + threadIdx.x;
  int lane = threadIdx.x & 63, w = threadIdx.x >> 6;
  int v = (i < n) ? ideg[i] : 0;
  int x = v;
#pragma unroll
  for (int o = 1; o < 64; o <<= 1) {
    int t = __shfl_up(x, o, 64);
    if (lane >= o) x += t;
  }
  if (lane == 63) wsh[w] = x;
  __syncthreads();
  int add = bsum[blockIdx.x];
  for (int k2 = 0; k2 < w; k2++) add += wsh[k2];
  int excl = add + x - v;
  if (i < n) {
    off[i] = excl;
    cursor[i] = excl;
  }
  if (i == n - 1) off[n] = excl + v;
}

// ---------------- megapre: {edge placement | bnode+bslot} ----------------
__global__ void k_megapre(const int* __restrict__ ei, const float* __restrict__ dinv,
                          int* __restrict__ cursor, int2* __restrict__ esw,
                          const int* __restrict__ off, int* __restrict__ bnode,
                          int* __restrict__ bslot) {
  int bx = blockIdx.x;
  if (bx < PLACEB) {
    int i = bx * 256 + threadIdx.x;
    if (i >= ETOT) return;
    int r_, c_;
    if (i < EE) {
      r_ = ei[i];
      c_ = ei[EE + i];
    } else {
      r_ = i - EE;
      c_ = i - EE;
    }
    int p = atomicAdd(&cursor[c_], 1);
    esw[p] = make_int2(r_, __float_as_int(dinv[r_] * dinv[c_]));
    return;
  }
  bx -= PLACEB;
  int g = bx * 256 + threadIdx.x;
  if (g >= NCHUNK) return;
  int e0 = g * CHUNK;
  int lo = 0, hi = NN;
  while (hi - lo > 1) {
    int mid = (lo + hi) >> 1;
    if (off[mid] <= e0) lo = mid; else hi = mid;
  }
  bnode[g] = lo;
  bslot[g] = (off[lo] + CHUNK - 1) / CHUNK;  // first chunk of node lo
}

__device__ __forceinline__ bool span_head(const int* bnode, const int* bslot, const int* off,
                                          int g, int& nd) {
  if (bslot[g] != g) return false;
  nd = bnode[g];
  int s = off[nd], e = off[nd + 1];
  return (s / CHUNK) != ((e - 1) / CHUNK);
}

// ---------------- MFMA expert GEMM (+ zeroc slice on blockIdx.y==4) -------
// grid (3125, 5). y<4: expert GEMM; y==4: zero spanning aggc slots.
__global__ __launch_bounds__(256) void k_matmfma(
    const float* __restrict__ A, int astr, int aoffPerEx,
    const f16* __restrict__ whiB, const f16* __restrict__ wloB,
    const float* __restrict__ biasB, int layer, f16* __restrict__ tout, int n,
    const int* __restrict__ bnode, const int* __restrict__ bslot,
    const int* __restrict__ off, float* __restrict__ aggc, CurvPack cp) {
  if (blockIdx.y == 4) {  // zeroc
    int g = blockIdx.x * 4 + (threadIdx.x >> 6);
    int lane = threadIdx.x & 63;
    if (g >= NCHUNK) return;
    int nd;
    if (!span_head(bnode, bslot, off, g, nd)) return;
    float2 z = make_float2(0.f, 0.f);
#pragma unroll
    for (int i = 0; i < 5; i++) ((float2*)aggc)[(size_t)g * 320 + i * 64 + lane] = z;
    return;
  }
  __shared__ float red[3][16][4];
  __shared__ float redT[16][4];
  __shared__ float nAs[16], nCs[16], nL[16];
  int ex = blockIdx.y;
  float kv = cp.k[ex], sk = cp.sk[ex], maxn = cp.mx[ex];
  const f16* whi = whiB + (size_t)(ex * 2 + layer) * 16384;
  const f16* wlo = wloB + (size_t)(ex * 2 + layer) * 16384;
  const float* biasb = biasB + (ex * 2 + layer) * 132;

  int tid = threadIdx.x;
  int w = tid >> 6;
  int lane = tid & 63;
  int col = lane & 15;
  int quad = lane >> 4;
  int n0w = blockIdx.x * 16;
  if (n0w >= n) return;

  int anodec = min(n0w + col, n - 1);
  const float* arow = A + (size_t)anodec * astr + ex * aoffPerEx;
  int jt0 = w * 2;

  f32x4 acc[2];
  acc[0] = (f32x4){0.f, 0.f, 0.f, 0.f};
  acc[1] = (f32x4){0.f, 0.f, 0.f, 0.f};
  float a_n2 = 0.f;

#pragma unroll
  for (int kc = 0; kc < 4; kc++) {
    int kb = kc * 32 + quad * 8;
    float4 a0 = *(const float4*)(arow + kb);
    float4 a1 = *(const float4*)(arow + kb + 4);
    float av[8] = {a0.x, a0.y, a0.z, a0.w, a1.x, a1.y, a1.z, a1.w};
    f16x8 Ah, Al;
#pragma unroll
    for (int i = 0; i < 8; i++) {
      a_n2 = fmaf(av[i], av[i], a_n2);
      f16 h = (f16)av[i];
      Ah[i] = h;
      Al[i] = (f16)(av[i] - (float)h);
    }
#pragma unroll
    for (int j2 = 0; j2 < 2; j2++) {
      const f16* bh = whi + (size_t)((jt0 + j2) * 16 + col) * 128 + kb;
      const f16* bl = wlo + (size_t)((jt0 + j2) * 16 + col) * 128 + kb;
      f16x8 Bh = *(const f16x8*)bh;
      f16x8 Bl = *(const f16x8*)bl;
      acc[j2] = __builtin_amdgcn_mfma_f32_16x16x32_f16(Ah, Bh, acc[j2], 0, 0, 0);
      acc[j2] = __builtin_amdgcn_mfma_f32_16x16x32_f16(Ah, Bl, acc[j2], 0, 0, 0);
      acc[j2] = __builtin_amdgcn_mfma_f32_16x16x32_f16(Al, Bh, acc[j2], 0, 0, 0);
    }
  }
  a_n2 += __shfl_xor(a_n2, 16, 64);
  a_n2 += __shfl_xor(a_n2, 32, 64);

  float bpj[2];
  bpj[0] = biasb[jt0 * 16 + col];
  bpj[1] = biasb[(jt0 + 1) * 16 + col];
  float y2 = biasb[128];

#pragma unroll
  for (int r = 0; r < 4; r++) {
    float s0 = 0.f, s1 = 0.f, s2 = 0.f;
#pragma unroll
    for (int j2 = 0; j2 < 2; j2++) {
      float v = acc[j2][r];
      s0 = fmaf(v, v, s0);
      s1 += fabsf(v);
      s2 = fmaf(v, bpj[j2], s2);
    }
#pragma unroll
    for (int m = 1; m < 16; m <<= 1) {
      s0 += __shfl_xor(s0, m, 64);
      s1 += __shfl_xor(s1, m, 64);
      s2 += __shfl_xor(s2, m, 64);
    }
    if (col == 0) {
      red[0][quad * 4 + r][w] = s0;
      red[1][quad * 4 + r][w] = s1;
      red[2][quad * 4 + r][w] = s2;
    }
  }
  __syncthreads();

  if (tid < 16) {
    float nraw0 = sqrtf(a_n2);
    float nnv0 = fmaxf(nraw0, 1e-15f);
    float tk0 = tan_k_d(nnv0, kv, sk);
    float pn0 = fmaxf(fabsf(tk0) * (nraw0 / nnv0), 1e-15f);
    float ps0 = proj_scale_d(pn0, kv, maxn);
    float sc = (tk0 / nnv0) * ps0;
    float xnr = pn0 * ps0;

    float s0f = (red[0][tid][0] + red[0][tid][1] + red[0][tid][2] + red[0][tid][3]) * sc * sc;
    float s1f = (red[1][tid][0] + red[1][tid][1] + red[1][tid][2] + red[1][tid][3]) * fabsf(sc);
    float s2f = (red[2][tid][0] + red[2][tid][1] + red[2][tid][2] + red[2][tid][3]) * sc;
    float xn = fmaxf(xnr, 1e-15f);
    float mxraw = sqrtf(s0f);
    float mxv = fmaxf(mxraw, 1e-15f);
    float ar = artan_k_d(xn, kv, sk);
    float c1 = tan_k_d(mxv / xn * ar, kv, sk);
    float s = (s1f == 0.f) ? 0.f : c1 / mxv;
    float pn = fmaxf(fabsf(c1) * (mxraw / mxv), 1e-15f);
    float ps = (s1f == 0.f) ? 1.f : proj_scale_d(pn, kv, maxn);
    s *= ps;
    float x2 = (s * s) * s0f;
    float xy = s * s2f;
    float Aa = 1.f - 2.f * kv * xy - kv * y2;
    float Cc = 1.f + kv * x2;
    float den = fmaxf(1.f - 2.f * kv * xy + (kv * kv) * x2 * y2, 1e-15f);
    nAs[tid] = Aa * s / den * sc;
    nCs[tid] = Cc / den;
  }
  __syncthreads();

#pragma unroll
  for (int r = 0; r < 4; r++) {
    int idx = quad * 4 + r;
    float Asc = nAs[idx], Cs = nCs[idx];
    float t0 = 0.f;
#pragma unroll
    for (int j2 = 0; j2 < 2; j2++) {
      float v = fmaf(Asc, acc[j2][r], Cs * bpj[j2]);
      t0 = fmaf(v, v, t0);
    }
#pragma unroll
    for (int m = 1; m < 16; m <<= 1) t0 += __shfl_xor(t0, m, 64);
    if (col == 0) redT[idx][w] = t0;
  }
  __syncthreads();

  if (tid < 16) {
    float t0f = redT[tid][0] + redT[tid][1] + redT[tid][2] + redT[tid][3];
    float nraw = sqrtf(t0f);
    float ps2 = proj_scale_d(fmaxf(nraw, 1e-15f), kv, maxn);
    float nh = fmaxf(ps2 * nraw, 1e-15f);
    nL[tid] = artan_k_d(nh, kv, sk) / nh * ps2;
  }
  __syncthreads();

#pragma unroll
  for (int r = 0; r < 4; r++) {
    int idx = quad * 4 + r;
    int gnode = n0w + idx;
    if (gnode >= n) continue;
    float Asc = nAs[idx], Cs = nCs[idx], L = nL[idx];
    f16* trow = tout + (size_t)gnode * 512;
#pragma unroll
    for (int j2 = 0; j2 < 2; j2++) {
      float v = fmaf(Asc, acc[j2][r], Cs * bpj[j2]);
      int d = (jt0 + j2) * 16 + col;
      trow[(d >> 1) * 8 + ex * 2 + (d & 1)] = (f16)(L * v);
    }
  }
}

// ---------------- fused multi-expert + gate edge sweep ----------------
// MODE 0: layer-1 experts -> agg1 (raw fp32) ; gate hidden (32-dim, m1) -> g1 relu
// MODE 1: layer-2 experts -> logmap0(expmap0) pooling into feats ;
//         gate: gather g1 (32-dim fp32), apply gw2 matvec at run flush (linearity),
//         relu + pool into hgate. gate2 GEMM eliminated.
template <int MODE>
__global__ __launch_bounds__(256) void k_aggF(
    const int2* __restrict__ esw, const int* __restrict__ off,
    const int* __restrict__ bnode, const int* __restrict__ bslot,
    const int* __restrict__ batch, const f16x8* __restrict__ t,
    const float* __restrict__ gsrc, float* __restrict__ agg1, float* __restrict__ aggc,
    float* __restrict__ g1out, float* __restrict__ feats,
    const float* __restrict__ gbias, const float* __restrict__ gw2,
    float* __restrict__ hgate, int etot, CurvPack cp) {
  __shared__ float gw2s[(MODE == 1) ? 32 : 1][128];
  if (MODE == 1) {  // stage gw2^T in LDS (before any divergent return)
#pragma unroll
    for (int i2 = 0; i2 < 16; i2++) {
      int u = threadIdx.x + i2 * 256;
      gw2s[u >> 7][u & 127] = gw2[(u & 127) * 32 + (u >> 7)];
    }
    __syncthreads();
  }
  int gw = blockIdx.x * 4 + (threadIdx.x >> 6);
  int lane = threadIdx.x & 63;
  int e0 = gw * CHUNK;
  if (e0 >= etot) return;
  int e1 = min(e0 + CHUNK, etot);
  int lane31 = lane & 31;
  int bnHead = bnode[gw];
  int slotA = bslot[gw];
  int slotB = ((gw + 1) * CHUNK < etot) ? bslot[gw + 1] : slotA;

  // whole-chunk edge metadata: lane l holds edges e0+l and e0+64+l
  int2 mv0 = esw[min(e0 + lane, etot - 1)];
  int2 mv1 = esw[min(e0 + 64 + lane, etot - 1)];
  // register windows for run offsets and batch ids (readlane, uniform index)
  int offv = off[min(bnHead + lane, NN)];
  int batchv = 0;
  if (MODE == 1) batchv = batch[min(bnHead + lane, NN - 1)];

  int cur = bnHead;
  int runStart = __builtin_amdgcn_readlane(offv, 0);
  int eend = __builtin_amdgcn_readlane(offv, 1);

  auto nextOff = [&](int c1) -> int {
    int rel = c1 - bnHead;
    if (rel < 64) return __builtin_amdgcn_readlane(offv, rel);
    return off[c1];
  };
  auto curBatch = [&](int c) -> int {
    int rel = c - bnHead;
    if (rel < 64) return __builtin_amdgcn_readlane(batchv, rel);
    return batch[c];
  };

  float ax[4], ay[4], pax[4], pay[4];
#pragma unroll
  for (int e = 0; e < 4; e++) ax[e] = ay[e] = pax[e] = pay[e] = 0.f;
  float gx = 0.f, pgx = 0.f, pgy = 0.f;
  int bcur = (MODE == 1) ? __builtin_amdgcn_readlane(batchv, 0) : 0;
  float bbx, bby = 0.f;
  if (MODE == 0) {
    bbx = gbias[lane31];
  } else {
    float2 bb = ((const float2*)gbias)[lane];
    bbx = bb.x;
    bby = bb.y;
  }

  auto flushInterior = [&]() {
#pragma unroll
    for (int e = 0; e < 4; e++) {
      if (MODE == 0) {
        ((float2*)agg1)[(size_t)cur * 256 + e * 64 + lane] = make_float2(ax[e], ay[e]);
      } else {
        float n2 = wsum64(fmaf(ax[e], ax[e], ay[e] * ay[e]));
        if (n2 <= cp.thr2[e]) {
          pax[e] += ax[e];
          pay[e] += ay[e];
        } else {
          float nraw = sqrtf(n2);
          float nnv = fmaxf(nraw, 1e-15f);
          float tk = tan_k_d(nnv, cp.k[e], cp.sk[e]);
          float s = tk / nnv;
          float pn = fmaxf(fabsf(tk) * (nraw / nnv), 1e-15f);
          float ps = proj_scale_d(pn, cp.k[e], cp.mx[e]);
          s *= ps;
          float nh = fmaxf(pn * ps, 1e-15f);
          float sc = artan_k_d(nh, cp.k[e], cp.sk[e]) / nh * s;
          pax[e] = fmaf(sc, ax[e], pax[e]);
          pay[e] = fmaf(sc, ay[e], pay[e]);
        }
      }
    }
    if (MODE == 0) {
      if (lane < 32) g1out[(size_t)cur * 32 + lane] = fmaxf(gx + bbx, 0.f);
    } else {
      // gate matvec: out = ag @ gw2^T ; ag[k] broadcast from lane k
      float o0 = 0.f, o1 = 0.f;
#pragma unroll
      for (int k2 = 0; k2 < 32; k2++) {
        float agk = __int_as_float(__builtin_amdgcn_readlane(__float_as_int(gx), k2));
        float2 wv = *(const float2*)&gw2s[k2][lane * 2];
        o0 = fmaf(agk, wv.x, o0);
        o1 = fmaf(agk, wv.y, o1);
      }
      pgx += fmaxf(o0 + bbx, 0.f);
      pgy += fmaxf(o1 + bby, 0.f);
    }
  };
  auto flushBoundary = [&]() {
    int slot = (cur == bnHead) ? slotA : slotB;
    float* dp = aggc + (size_t)slot * 640;
#pragma unroll
    for (int e = 0; e < 4; e++) {
      atomicAdd(dp + e * 128 + lane * 2, ax[e]);
      atomicAdd(dp + e * 128 + lane * 2 + 1, ay[e]);
    }
    if (lane < 32) atomicAdd(dp + 512 + lane, gx);
  };
  auto flushPool = [&]() {
#pragma unroll
    for (int e = 0; e < 4; e++) {
      float* fp = &feats[(size_t)bcur * 512 + e * 128 + lane * 2];
      atomicAdd(fp, pax[e]);
      atomicAdd(fp + 1, pay[e]);
    }
    float* hp = &hgate[(size_t)bcur * 128 + lane * 2];
    atomicAdd(hp, pgx);
    atomicAdd(hp + 1, pgy);
  };

  f16x8 rv[8];
  float gf[8];

#pragma unroll
  for (int b = 0; b < CHUNK / 8; b++) {
    int jb = e0 + b * 8;
    if (jb < e1) {
      const int2 mvsel = (b < 8) ? mv0 : mv1;
#pragma unroll
      for (int q = 0; q < 8; q++) {
        int s = __builtin_amdgcn_readlane(mvsel.x, (b & 7) * 8 + q);
        rv[q] = t[(size_t)s * 64 + lane];
        gf[q] = gsrc[(size_t)s * 32 + lane31];
      }
#pragma unroll
      for (int q = 0; q < 8; q++) {
        if (jb + q == eend) {
          if (runStart >= e0) flushInterior(); else flushBoundary();
#pragma unroll
          for (int e = 0; e < 4; e++) ax[e] = ay[e] = 0.f;
          gx = 0.f;
          runStart = jb + q;
          cur++;
          eend = nextOff(cur + 1);
          if (MODE == 1) {
            int nbt = curBatch(cur);
            if (nbt != bcur) {
              flushPool();
#pragma unroll
              for (int e = 0; e < 4; e++) pax[e] = pay[e] = 0.f;
              pgx = pgy = 0.f;
              bcur = nbt;
            }
          }
        }
        float w = __int_as_float(__builtin_amdgcn_readlane(mvsel.y, (b & 7) * 8 + q));
#pragma unroll
        for (int e = 0; e < 4; e++) {
          ax[e] = fmaf(w, (float)rv[q][2 * e], ax[e]);
          ay[e] = fmaf(w, (float)rv[q][2 * e + 1], ay[e]);
        }
        gx = fmaf(w, gf[q], gx);
      }
    }
  }
  if (runStart >= e0 && eend <= e1) flushInterior(); else flushBoundary();
  if (MODE == 1) flushPool();
}

// ---------------- fixups for chunk-spanning runs ----------------
__global__ void k_fix1(const int* __restrict__ bnode, const int* __restrict__ bslot,
                       const int* __restrict__ off, const float* __restrict__ aggc,
                       float* __restrict__ agg1, float* __restrict__ g1,
                       const float* __restrict__ gb1, int nchunk) {
  int g = blockIdx.x * 4 + (threadIdx.x >> 6);
  int lane = threadIdx.x & 63;
  if (g >= nchunk) return;
  int nd;
  if (!span_head(bnode, bslot, off, g, nd)) return;
  const float* sp = aggc + (size_t)g * 640;
#pragma unroll
  for (int e = 0; e < 4; e++) {
    float2 v = ((const float2*)sp)[e * 64 + lane];
    ((float2*)agg1)[(size_t)nd * 256 + e * 64 + lane] = v;
  }
  if (lane < 32) g1[(size_t)nd * 32 + lane] = fmaxf(sp[512 + lane] + gb1[lane], 0.f);
}

__global__ void k_fix2(const int* __restrict__ bnode, const int* __restrict__ bslot,
                       const int* __restrict__ off, const float* __restrict__ aggc,
                       const int* __restrict__ batch, float* __restrict__ feats,
                       const float* __restrict__ gb2, const float* __restrict__ gw2,
                       float* __restrict__ hgate, int nchunk, CurvPack cp) {
  int g = blockIdx.x * 4 + (threadIdx.x >> 6);
  int lane = threadIdx.x & 63;
  if (g >= nchunk) return;
  int nd;
  if (!span_head(bnode, bslot, off, g, nd)) return;
  int b = batch[nd];
  const float* sp = aggc + (size_t)g * 640;
#pragma unroll
  for (int e = 0; e < 4; e++) {
    float2 v = ((const float2*)sp)[e * 64 + lane];
    float n2 = wsum64(fmaf(v.x, v.x, v.y * v.y));
    float nraw = sqrtf(n2);
    float nnv = fmaxf(nraw, 1e-15f);
    float tk = tan_k_d(nnv, cp.k[e], cp.sk[e]);
    float s = tk / nnv;
    float pn = fmaxf(fabsf(tk) * (nraw / nnv), 1e-15f);
    float ps = proj_scale_d(pn, cp.k[e], cp.mx[e]);
    s *= ps;
    float nh = fmaxf(pn * ps, 1e-15f);
    float sc = artan_k_d(nh, cp.k[e], cp.sk[e]) / nh * s;
    float* fp = &feats[(size_t)b * 512 + e * 128 + lane * 2];
    atomicAdd(fp, sc * v.x);
    atomicAdd(fp + 1, sc * v.y);
  }
  // gate: matvec of spanning-node ag with gw2, relu, pool
  float2 bb = ((const float2*)gb2)[lane];
  float o0 = 0.f, o1 = 0.f;
#pragma unroll 8
  for (int k2 = 0; k2 < 32; k2++) {
    float agk = sp[512 + k2];
    o0 = fmaf(agk, gw2[(2 * lane) * 32 + k2], o0);
    o1 = fmaf(agk, gw2[(2 * lane + 1) * 32 + k2], o1);
  }
  float* hp = &hgate[(size_t)b * 128 + lane * 2];
  atomicAdd(hp, fmaxf(o0 + bb.x, 0.f));
  atomicAdd(hp + 1, fmaxf(o1 + bb.y, 0.f));
}

// ---------------- final ----------------
__global__ __launch_bounds__(128) void k_final(const float* __restrict__ feats,
                                               const float* __restrict__ hgate,
                                               const float* __restrict__ counts,
                                               const float* __restrict__ gate_u,
                                               const float* __restrict__ tau_raw,
                                               float* __restrict__ out, CurvPack cp) {
  __shared__ float l2[2];
  int b = blockIdx.x;
  int j = threadIdx.x;
  float cnt = fmaxf(counts[b], 1.f);
  float hg = hgate[(size_t)b * 128 + j] / cnt;

  auto bsum = [&](float v) -> float {
    v = wsum64(v);
    __syncthreads();
    if ((j & 63) == 0) l2[j >> 6] = v;
    __syncthreads();
    return l2[0] + l2[1];
  };

  float nhg2 = bsum(hg * hg);
  float nhgraw = sqrtf(nhg2);
  float nhg = fmaxf(nhgraw, 1e-15f);

  float d[4], tau[4];
#pragma unroll
  for (int i = 0; i < 4; i++) {
    float kv = cp.k[i], sk = cp.sk[i], mxn = cp.mx[i];
    float tk = tan_k_d(nhg, kv, sk);
    float s = tk / nhg;
    float pn = fmaxf(fabsf(tk) * (nhgraw / nhg), 1e-15f);
    s *= proj_scale_d(pn, kv, mxn);
    float zk = s * hg;

    float u = gate_u[i * 128 + j];
    float nu2 = bsum(u * u);
    float nuraw = sqrtf(nu2);
    float nu = fmaxf(nuraw, 1e-15f);
    float tku = tan_k_d(nu, kv, sk);
    float su = tku / nu;
    float pnu = fmaxf(fabsf(tku) * (nuraw / nu), 1e-15f);
    su *= proj_scale_d(pnu, kv, mxn);
    float yk = su * u;

    float xv = -zk;
    float x2 = bsum(xv * xv);
    float y2 = bsum(yk * yk);
    float xy = bsum(xv * yk);
    float A = 1.f - 2.f * kv * xy - kv * y2;
    float C = 1.f + kv * x2;
    float den = fmaxf(1.f - 2.f * kv * xy + (kv * kv) * x2 * y2, 1e-15f);
    float ma = (A * xv + C * yk) / den;
    float m2 = bsum(ma * ma);
    float mraw = sqrtf(m2);
    float ps2 = proj_scale_d(fmaxf(mraw, 1e-15f), kv, mxn);
    float nm = fmaxf(ps2 * mraw, 1e-15f);
    d[i] = 2.f * artan_k_d(nm, kv, sk);

    float tr = tau_raw[i];
    tau[i] = fminf(fmaxf(log1pf(expf(tr)) + 0.05f, 0.05f), 10.f);
  }

  float xi[4];
  float mxv = -1e30f;
#pragma unroll
  for (int i = 0; i < 4; i++) {
    xi[i] = -d[i] / tau[i];
    mxv = fmaxf(mxv, xi[i]);
  }
  float es = 0.f, e[4];
#pragma unroll
  for (int i = 0; i < 4; i++) {
    e[i] = expf(xi[i] - mxv);
    es += e[i];
  }
  float w[4];
#pragma unroll
  for (int i = 0; i < 4; i++) w[i] = e[i] / es;

#pragma unroll
  for (int i = 0; i < 4; i++)
    out[(size_t)b * 512 + i * 128 + j] = feats[(size_t)b * 512 + i * 128 + j] / cnt * w[i];

  if (j < 4) {
    out[65536 + b * 4 + j] = w[j];
    out[66048 + b * 4 + j] = d[j];
  }
  if (b == 0 && j < 4) out[66560 + j] = tau[j];
}

// ---------------- host launcher ----------------
extern "C" void kernel_launch(void* const* d_in, const int* in_sizes, int n_in,
                              void* d_out, int out_size, void* d_ws, size_t ws_size,
                              hipStream_t stream) {
  const float* x = (const float*)d_in[0];
  const int* ei = (const int*)d_in[1];
  const int* batch = (const int*)d_in[2];
  const float* ew1 = (const float*)d_in[3];
  const float* eb1 = (const float*)d_in[4];
  const float* ew2 = (const float*)d_in[5];
  const float* eb2 = (const float*)d_in[6];
  const float* gw1 = (const float*)d_in[7];
  const float* gb1 = (const float*)d_in[8];
  const float* gw2 = (const float*)d_in[9];
  const float* gb2 = (const float*)d_in[10];
  const float* gu = (const float*)d_in[11];
  const float* traw = (const float*)d_in[12];
  float* out = (float*)d_out;

  const int N = NN, E = EE, ET = ETOT, B = BB;

  float* ws = (float*)d_ws;
  size_t o = 0;
  f16* t4 = (f16*)ws;       o += (size_t)N * 256;   // N*512 halfs, granule-interleaved
  float* agg1 = ws + o;     o += (size_t)N * 512;   // layer-1 raw agg, [node][ex*128+d]
  float* aggc = ws + o;     o += (size_t)NCHUNK * 640;  // boundary accum (512 exp + 32 gate)
  float* deg = ws + o;      o += N;                 // zeroed; becomes dinv
  float* counts = ws + o;   o += 256;
  float* feats = ws + o;    o += (size_t)B * 512;
  float* hg = ws + o;       o += (size_t)B * 128;
  float* biasb = ws + o;    o += 8 * 132;
  f16* whi = (f16*)(ws + o);    o += 8 * 16384 / 2;
  f16* wlo = (f16*)(ws + o);    o += 8 * 16384 / 2;
  float* m1 = ws + o;       o += (size_t)N * 32;    // gate hidden pre-agg
  float* g1 = ws + o;       o += (size_t)N * 32;    // gate hidden post-relu
  int* ideg = (int*)(ws + o);   o += N;
  int* csroff = (int*)(ws + o); o += N + 8;
  int* cursor = (int*)(ws + o); o += N;
  int* boff = (int*)(ws + o);   o += 136;
  int* bsum = (int*)(ws + o);   o += 256;
  int* bnode = (int*)(ws + o);  o += NCHUNK + 8;
  int* bslot = (int*)(ws + o);  o += NCHUNK + 8;
  int2* esw = (int2*)(ws + o);  o += (size_t)2 * ET;

  // zero deg + counts + feats + hg in one memset (contiguous)
  hipMemsetAsync(deg, 0, ((size_t)N + 256 + (size_t)B * 512 + (size_t)B * 128) * sizeof(float),
                 stream);

  const double curvs[4] = {-1.0, 0.0, 1.0, -0.5};
  CurvPack cp;
  for (int i = 0; i < 4; i++) {
    double kd = curvs[i];
    double skd = sqrt(fabs(kd));
    cp.k[i] = (float)kd;
    cp.sk[i] = (float)skd;
    cp.mx[i] = (kd < 0) ? (float)((1.0 - 1e-5) / skd) : 3.0e38f;
    if (kd < 0) {
      double thr = 6.0 / skd;
      cp.thr2[i] = (float)(thr * thr);
    } else if (kd > 0) {
      double thr = 1.5 / skd;
      cp.thr2[i] = (float)(thr * thr);
    } else {
      cp.thr2[i] = 3.0e38f;
    }
  }

  k_mega0<<<MEGA0B, 256, 0, stream>>>(ei, deg, batch, boff, counts, eb1, eb2, biasb, ew1, ew2,
                                      whi, wlo, x, gw1, m1, cp);
  k_dinv<<<SCB, 256, 0, stream>>>(deg, ideg, N);
  k_scanA<<<SCB, 256, 0, stream>>>(ideg, bsum, N);
  k_scanB<<<1, 256, 0, stream>>>(bsum, SCB);
  k_scanC<<<SCB, 256, 0, stream>>>(ideg, bsum, csroff, cursor, N);
  k_megapre<<<PLACEB + BNB, 256, 0, stream>>>(ei, deg, cursor, esw, csroff, bnode, bslot);

  const int aggBlocks = (NCHUNK + 3) / 4;
  dim3 mfmaGrid((N + 15) / 16, 5);  // y=4 is the fused zeroc slice

  // ---- layer 1 (all 4 experts fused) + gate hidden ----
  k_matmfma<<<mfmaGrid, 256, 0, stream>>>(x, 128, 0, whi, wlo, biasb, 0, t4, N, bnode, bslot,
                                          csroff, aggc, cp);
  k_aggF<0><<<aggBlocks, 256, 0, stream>>>(esw, csroff, bnode, bslot, batch, (const f16x8*)t4,
                                           m1, agg1, aggc, g1, nullptr, gb1, nullptr, nullptr,
                                           ET, cp);
  k_fix1<<<aggBlocks, 256, 0, stream>>>(bnode, bslot, csroff, aggc, agg1, g1, gb1, NCHUNK);

  // ---- layer 2 + gate (gw2 folded into flush) ----
  k_matmfma<<<mfmaGrid, 256, 0, stream>>>(agg1, 512, 128, whi, wlo, biasb, 1, t4, N, bnode,
                                          bslot, csroff, aggc, cp);
  k_aggF<1><<<aggBlocks, 256, 0, stream>>>(esw, csroff, bnode, bslot, batch, (const f16x8*)t4,
                                           g1, nullptr, aggc, nullptr, feats, gb2, gw2, hg, ET,
                                           cp);
  k_fix2<<<aggBlocks, 256, 0, stream>>>(bnode, bslot, csroff, aggc, batch, feats, gb2, gw2, hg,
                                        NCHUNK, cp);

  k_final<<<B, 128, 0, stream>>>(feats, hg, counts, gu, traw, out, cp);

  (void)in_sizes; (void)n_in; (void)out_size; (void)ws_size;
}